// Round 32
// baseline (230.624 us; speedup 1.0000x reference)
//
#include <hip/hip_runtime.h>
#include <hip/hip_bf16.h>
#include <math.h>

// Problem constants
#define BB 4
#define CC 128
#define NN 4096      // H*W
#define DD 256
#define INNER 512
#define FFD 1024
#define PP 4
#define LL 2
#define NT 8
#define SS 1024      // NN/PP
#define SCALE 0.0625f // 1/sqrt(256)

typedef __attribute__((ext_vector_type(8))) short bf16x8;
typedef __attribute__((ext_vector_type(8))) short short8;
typedef __attribute__((ext_vector_type(4))) short short4v;
typedef __attribute__((ext_vector_type(4))) float f32x4;

#define GLD_LDS16(g, l) __builtin_amdgcn_global_load_lds( \
    (const __attribute__((address_space(1))) void*)(g), \
    (__attribute__((address_space(3))) void*)(l), 16, 0, 0)

template<int NW>
__device__ inline float block_sum(float v, float* sbuf){
  #pragma unroll
  for (int mk=32; mk; mk>>=1) v += __shfl_xor(v, mk);
  int w = threadIdx.x>>6;
  if ((threadIdx.x&63)==0) sbuf[w]=v;
  __syncthreads();
  float r = 0.f;
  #pragma unroll
  for (int k=0;k<NW;k++) r += sbuf[k];
  __syncthreads();
  return r;
}

__device__ inline unsigned short bf16bits(float v){
  __hip_bfloat16 t = __float2bfloat16(v);
  unsigned short u;
  __builtin_memcpy(&u, &t, 2);
  return u;
}
__device__ inline float bf2f(unsigned short u){
  unsigned int x = ((unsigned int)u)<<16;
  float f;
  __builtin_memcpy(&f, &x, 4);
  return f;
}

// fast GELU: erf via Abramowitz-Stegun 7.1.26 (|eps| <= 1.5e-7)
__device__ inline float gelu_f(float x){
  float z  = x * 0.70710678118654752440f;
  float az = fabsf(z);
  float t  = 1.0f / (1.0f + 0.3275911f*az);
  float y  = t*(0.254829592f + t*(-0.284496736f + t*(1.421413741f +
             t*(-1.453152027f + t*1.061405429f))));
  float erfv = 1.0f - y*__expf(-az*az);
  erfv = (z < 0.0f) ? -erfv : erfv;
  return 0.5f*x*(1.0f+erfv);
}

// K0: scorer (kk2/kb/vsc), 32 blocks
__global__ __launch_bounds__(256) void scorer_kernel(
    const float* __restrict__ m, const float* __restrict__ sk_w,
    const float* __restrict__ sk_b, const float* __restrict__ sv_w,
    const float* __restrict__ sv_b, const float* __restrict__ sq_w,
    const float* __restrict__ sq_b,
    float* __restrict__ kk2, float* __restrict__ kb, float* __restrict__ vsc)
{
  __shared__ float ms[256];
  __shared__ float ks[256];
  __shared__ float sbuf[4];
  int bj = blockIdx.x;
  int tid = threadIdx.x;
  ms[tid] = m[bj*DD + tid];
  __syncthreads();
  float acc=0.f;
  #pragma unroll 8
  for(int c=0;c<DD;c++) acc = fmaf(ms[c], sk_w[c*DD + tid], acc);
  ks[tid] = acc + sk_b[tid];
  float sv = block_sum<4>(ms[tid]*sv_w[tid], sbuf);
  if(tid==0) vsc[bj] = sv + sv_b[0];
  __syncthreads();
  const float* wr = sq_w + (long)tid*DD;
  float a2 = 0.f;
  #pragma unroll 4
  for (int c=0; c<DD; c+=4){
    float4 wvv = *(const float4*)(wr + c);
    a2 = fmaf(wvv.x, ks[c+0], fmaf(wvv.y, ks[c+1], fmaf(wvv.z, ks[c+2], fmaf(wvv.w, ks[c+3], a2))));
  }
  kk2[bj*DD + tid] = a2;
  float kbv = block_sum<4>(sq_b[tid]*ks[tid], sbuf);
  if (tid==0) kb[bj] = kbv;
}

// K1 MERGED, latency-bound work FIRST: [0,256) K/V; [256,1536) wconv;
// [1536,2560) proj+LN+scores. proj x reads are block-uniform -> scalar loads.
__global__ __launch_bounds__(256) void proj_prep_kernel(
    const float* __restrict__ x, const float* __restrict__ proj_w,
    const float* __restrict__ proj_b, const float* __restrict__ lnp_g,
    const float* __restrict__ lnp_b, const float* __restrict__ kk2,
    const float* __restrict__ kb, const float* __restrict__ vsc,
    float* __restrict__ tokens, float* __restrict__ scores,
    int* __restrict__ rank, long long* __restrict__ psumsI,
    const float* __restrict__ m, const float* __restrict__ an_g,
    const float* __restrict__ an_b, const float* __restrict__ wk,
    const float* __restrict__ wv, float* __restrict__ kvk,
    float* __restrict__ kvv,
    const float* __restrict__ wq, const float* __restrict__ w1,
    const float* __restrict__ w2,
    __hip_bfloat16* __restrict__ wqT, __hip_bfloat16* __restrict__ w1T,
    __hip_bfloat16* __restrict__ w2T)
{
  __shared__ union {
    struct {
      float ys[16][260];
      float kj[8][260];
      float kbs[8], vs[8], mu_s[16], rs_s[16];
      float lg[16][8];
    } pr;
    struct { float t[64][65]; } wc;
    struct { float mn[256]; float sbuf[4]; } kv;
  } sm;
  int z = blockIdx.x;
  int tid = threadIdx.x;

  if (z < 256){
    // ---- K/V precompute (latency-bound, dispatch first) ----
    float* mn = sm.kv.mn;
    float* sbuf = sm.kv.sbuf;
    int idx = z;
    int j = idx & 7, b = (idx>>3)&3, pl = idx>>5;
    float v = m[(b*NT+j)*DD + tid];
    float s = block_sum<4>(v, sbuf);
    float mu = s*(1.0f/256.0f);
    float dv = v-mu;
    float q = block_sum<4>(dv*dv, sbuf);
    float rs = rsqrtf(q*(1.0f/256.0f)+1e-5f);
    mn[tid] = dv*rs*an_g[pl*DD+tid] + an_b[pl*DD+tid];
    __syncthreads();
    float ka0=0.f, va0=0.f, ka1=0.f, va1=0.f;
    const float* wkb = wk + (long)pl*DD*INNER;
    const float* wvb = wv + (long)pl*DD*INNER;
    #pragma unroll 8
    for (int c=0;c<DD;c++){
      float mc = mn[c];
      const float* wkr = wkb + (long)c*INNER;
      const float* wvr = wvb + (long)c*INNER;
      ka0 = fmaf(mc, wkr[tid], ka0);
      ka1 = fmaf(mc, wkr[tid+256], ka1);
      va0 = fmaf(mc, wvr[tid], va0);
      va1 = fmaf(mc, wvr[tid+256], va1);
    }
    long off = ((long)pl*BB + b)*(NT*INNER) + j*INNER;
    kvk[off+tid]=ka0; kvk[off+tid+256]=ka1;
    kvv[off+tid]=va0; kvv[off+tid+256]=va1;
  } else if (z < 1536){
    // ---- weight convert+transpose (latency-bound) ----
    int z2 = z - 256;
    const float* src; __hip_bfloat16* dst; int K, N, rel;
    if (z2 < 256)      { src=wq; dst=wqT; K=DD;   N=INNER; rel=z2; }
    else if (z2 < 768) { src=w1; dst=w1T; K=DD;   N=FFD;   rel=z2-256; }
    else               { src=w2; dst=w2T; K=FFD;  N=DD;    rel=z2-768; }
    int tn = N>>6, tk = K>>6, per = tn*tk;
    int pl = rel/per, r2 = rel%per;
    int n0 = (r2%tn)*64, k0 = (r2/tn)*64;
    float (*t)[65] = sm.wc.t;
    #pragma unroll
    for (int i=0;i<4;i++){
      int idx = i*256+tid;
      int kk = idx>>4, n4 = idx&15;
      float4 v = *(const float4*)&src[((long)pl*K + k0+kk)*N + n0 + n4*4];
      t[kk][n4*4+0]=v.x; t[kk][n4*4+1]=v.y; t[kk][n4*4+2]=v.z; t[kk][n4*4+3]=v.w;
    }
    __syncthreads();
    #pragma unroll
    for (int i=0;i<4;i++){
      int idx = i*256+tid;
      int nn = idx>>4, k4 = idx&15;
      short4v o;
      o[0] = (short)bf16bits(t[k4*4+0][nn]);
      o[1] = (short)bf16bits(t[k4*4+1][nn]);
      o[2] = (short)bf16bits(t[k4*4+2][nn]);
      o[3] = (short)bf16bits(t[k4*4+3][nn]);
      *(short4v*)&dst[((long)pl*N + n0+nn)*K + k0 + k4*4] = o;
    }
  } else {
    // ---- proj + LN + scores (compute-bound, streams in behind prep) ----
    int zz = z - 1536;
    int b  = zz >> 8;
    int n0 = (zz & 255) * 16;
    if (tid < 16) rank[b*NN + n0 + tid] = 0;
    if (zz == 0 && tid < 16) psumsI[tid] = 0;
    float (*ys)[260] = sm.pr.ys;
    float (*kj)[260] = sm.pr.kj;
    float* kbs = sm.pr.kbs; float* vs = sm.pr.vs;
    float* mu_s = sm.pr.mu_s; float* rs_s = sm.pr.rs_s;
    float (*lg)[8] = sm.pr.lg;
    #pragma unroll
    for (int i=0;i<8;i++){
      int idx = i*256 + tid;
      int r = idx >> 8, c = idx & 255;
      kj[r][c] = kk2[(b*NT + r)*DD + c];
    }
    if (tid < 8){ kbs[tid] = kb[b*NT+tid]; vs[tid] = vsc[b*NT+tid]; }
    float acc[16];
    #pragma unroll
    for (int t=0;t<16;t++) acc[t]=0.f;
    const float* xb = x + (long)(b*CC)*NN + n0;
    for (int c0=0;c0<CC;c0+=4){
      float w0 = proj_w[(c0+0)*DD + tid];
      float w1_ = proj_w[(c0+1)*DD + tid];
      float w2_ = proj_w[(c0+2)*DD + tid];
      float w3_ = proj_w[(c0+3)*DD + tid];
      const float* x0 = xb + (long)(c0+0)*NN;
      const float* x1 = xb + (long)(c0+1)*NN;
      const float* x2 = xb + (long)(c0+2)*NN;
      const float* x3 = xb + (long)(c0+3)*NN;
      #pragma unroll
      for (int t=0;t<16;t++){
        acc[t] = fmaf(x0[t],w0,fmaf(x1[t],w1_,fmaf(x2[t],w2_,fmaf(x3[t],w3_,acc[t]))));
      }
    }
    float pb = proj_b[tid];
    #pragma unroll
    for (int t=0;t<16;t++) ys[t][tid] = acc[t] + pb;
    __syncthreads();
    int w = tid>>6, lane = tid&63;
    for (int k=0;k<4;k++){
      int t = w*4+k;
      float s = ys[t][lane] + ys[t][lane+64] + ys[t][lane+128] + ys[t][lane+192];
      #pragma unroll
      for (int mk=32; mk; mk>>=1) s += __shfl_xor(s, mk);
      float mu = s*(1.0f/256.0f);
      float d0=ys[t][lane]-mu, d1=ys[t][lane+64]-mu, d2=ys[t][lane+128]-mu, d3=ys[t][lane+192]-mu;
      float q = d0*d0+d1*d1+d2*d2+d3*d3;
      #pragma unroll
      for (int mk=32; mk; mk>>=1) q += __shfl_xor(q, mk);
      if (lane==0){ mu_s[t]=mu; rs_s[t]=rsqrtf(q*(1.0f/256.0f)+1e-5f); }
    }
    __syncthreads();
    float g = lnp_g[tid], be = lnp_b[tid];
    #pragma unroll
    for (int t=0;t<16;t++){
      float nv = (ys[t][tid]-mu_s[t])*rs_s[t]*g + be;
      tokens[((long)(b*NN + n0 + t))*DD + tid] = nv;
      ys[t][tid] = nv;
    }
    __syncthreads();
    if (tid < 128){
      int t = tid>>3, j = tid&7;
      float a2 = 0.f;
      for (int c0=0;c0<DD;c0+=4){
        float4 tv = *(const float4*)&ys[t][c0];
        float4 kv2 = *(const float4*)&kj[j][c0];
        a2 = fmaf(tv.x,kv2.x,fmaf(tv.y,kv2.y,fmaf(tv.z,kv2.z,fmaf(tv.w,kv2.w,a2))));
      }
      lg[t][j] = (a2 + kbs[j]) * SCALE;
    }
    __syncthreads();
    if (tid < 16){
      float mx=-1e30f;
      #pragma unroll
      for(int j=0;j<NT;j++) mx=fmaxf(mx,lg[tid][j]);
      float s=0.f, sc=0.f;
      #pragma unroll
      for(int j=0;j<NT;j++){ float e=__expf(lg[tid][j]-mx); s+=e; sc+=e*vs[j]; }
      scores[b*NN + n0 + tid] = sc/s;
    }
  }
}

// K2 MERGED: blocks [0,256) qkvwo (first, depends only on kvk/kvv/wqT);
// [256,1280) partial ranks
__global__ __launch_bounds__(256) void rank_qkvwo_kernel(
    const float* __restrict__ scores, int* __restrict__ rank,
    const float* __restrict__ kvk, const float* __restrict__ kvv,
    const __hip_bfloat16* __restrict__ wqT, const float* __restrict__ wo,
    __hip_bfloat16* __restrict__ qkBuf, __hip_bfloat16* __restrict__ vwoT)
{
  __shared__ union {
    struct { float ss[256]; } rk;
    struct { float kL[8][64]; float vL[8][64]; } qv;
  } sm;
  int z = blockIdx.x;
  if (z >= 256){
    int zz = z - 256;
    int b  = zz >> 8;
    int it = (zz >> 4) & 15;
    int jt = zz & 15;
    int i = it*256 + threadIdx.x;
    float si = scores[b*NN + i];
    sm.rk.ss[threadIdx.x] = scores[b*NN + jt*256 + threadIdx.x];
    __syncthreads();
    int jbase = jt*256;
    int cnt = 0;
    #pragma unroll 4
    for (int j=0;j<256;j++){
      float sj = sm.rk.ss[j];
      cnt += (sj > si) || (sj == si && (jbase+j) < i);
    }
    atomicAdd(&rank[b*NN+i], cnt);
  } else {
    int zz = z;                      // z*8 + h
    int z3 = zz>>3, h = zz&7;
    int l = z3>>4, g = z3&15;
    int b = g>>2, p = g&3;
    int pl = p*LL + l;
    int c = threadIdx.x;
    float (*kL)[64] = sm.qv.kL;
    float (*vL)[64] = sm.qv.vL;
    {
      int j0 = c>>6, d0 = c&63;
      long off = ((long)pl*BB + b)*(NT*INNER) + h*64 + d0;
      kL[j0][d0]   = kvk[off + j0*INNER];
      vL[j0][d0]   = kvv[off + j0*INNER];
      kL[j0+4][d0] = kvk[off + (j0+4)*INNER];
      vL[j0+4][d0] = kvv[off + (j0+4)*INNER];
    }
    __syncthreads();
    float qa[8] = {0,0,0,0,0,0,0,0};
    float va[8] = {0,0,0,0,0,0,0,0};
    const __hip_bfloat16* wqp = wqT + ((long)pl*INNER + h*64)*DD + c;
    const float* wop = wo + ((long)pl*INNER + h*64)*DD + c;
    #pragma unroll 4
    for (int d=0; d<64; d++){
      float wqv = bf2f(*(const unsigned short*)(wqp + (long)d*DD));
      float wov = wop[(long)d*DD];
      #pragma unroll
      for (int j=0;j<8;j++){
        qa[j] = fmaf(kL[j][d], wqv, qa[j]);
        va[j] = fmaf(vL[j][d], wov, va[j]);
      }
    }
    __hip_bfloat16* qkg = qkBuf + (long)z3*64*256;
    __hip_bfloat16* vwg = vwoT + (long)z3*256*64;
    #pragma unroll
    for (int j=0;j<8;j++)
      qkg[(h*8+j)*256 + c] = __float2bfloat16(qa[j]*SCALE);
    short8 o;
    #pragma unroll
    for (int j=0;j<8;j++) o[j] = (short)bf16bits(va[j]);
    *(short8*)(vwg + c*64 + h*8) = o;
  }
}

// K3b: cidx + fixed-point partition score sums (hierarchical, deterministic)
__global__ __launch_bounds__(256) void rank_finalize_kernel(
    const int* __restrict__ rank, const float* __restrict__ scores,
    int* __restrict__ cidx, long long* __restrict__ psumsI)
{
  __shared__ unsigned long long bins[PP];
  if (threadIdx.x < PP) bins[threadIdx.x] = 0ull;
  __syncthreads();
  int b = blockIdx.x >> 4;
  int i = (blockIdx.x & 15)*256 + threadIdx.x;
  int rk = rank[b*NN + i];
  int p = rk >> 10;
  cidx[(b*PP + p)*SS + (rk & (SS-1))] = i;
  long long iv = (long long)llrintf(scores[b*NN + i] * 268435456.0f); // 2^28
  atomicAdd(&bins[p], (unsigned long long)iv);
  __syncthreads();
  if (threadIdx.x < PP)
    atomicAdd((unsigned long long*)&psumsI[b*PP + threadIdx.x], bins[threadIdx.x]);
}

// K6: gather + LN(an[p,0]) fused
__global__ __launch_bounds__(256) void gather_ln_kernel(
    const float* __restrict__ tokens, const int* __restrict__ cidx,
    float* __restrict__ Xc, __hip_bfloat16* __restrict__ Y,
    const float* __restrict__ gamma, const float* __restrict__ beta)
{
  long slot = (long)blockIdx.x*8 + (threadIdx.x>>5);
  int l32 = threadIdx.x & 31;
  int b = (int)(slot >> 12);
  int p = (int)((slot>>10)&3);
  int i = cidx[slot];
  const float* src = tokens + ((long)b*NN + i)*DD + l32*8;
  float4 v0 = *(const float4*)src;
  float4 v1 = *(const float4*)(src+4);
  *(float4*)(Xc + slot*DD + l32*8) = v0;
  *(float4*)(Xc + slot*DD + l32*8 + 4) = v1;
  float s = v0.x+v0.y+v0.z+v0.w+v1.x+v1.y+v1.z+v1.w;
  #pragma unroll
  for (int mk=16; mk; mk>>=1) s += __shfl_xor(s, mk);
  float mu = s*(1.0f/256.0f);
  float vv[8] = {v0.x,v0.y,v0.z,v0.w,v1.x,v1.y,v1.z,v1.w};
  float q = 0.f;
  #pragma unroll
  for (int k=0;k<8;k++){ float d = vv[k]-mu; q += d*d; }
  #pragma unroll
  for (int mk=16; mk; mk>>=1) q += __shfl_xor(q, mk);
  float rs = rsqrtf(q*(1.0f/256.0f)+1e-5f);
  short8 o;
  #pragma unroll
  for (int k=0;k<8;k++){
    int d = l32*8+k;
    o[k] = (short)bf16bits((vv[k]-mu)*rs*gamma[p*(LL*DD)+d]+beta[p*(LL*DD)+d]);
  }
  *(short8*)(Y + slot*DD + l32*8) = o;
}

// K9: FF1 GEMM, K=256 fully resident in LDS (128KB). Single stage + barrier,
// then 128 MFMAs with zero further synchronization. Grid (8,8,16).
__global__ __launch_bounds__(256) void ff1_gemm(
    const __hip_bfloat16* __restrict__ A, long astride,
    const __hip_bfloat16* __restrict__ BT, long bpstride,
    const float* __restrict__ bias, int bias_pstride,
    __hip_bfloat16* __restrict__ C, int ldc, long cstride)
{
  int g = blockIdx.z;
  int p = g & 3;
  const __hip_bfloat16* Ag = A  + (long)g*astride + (long)blockIdx.x*128*DD;
  const __hip_bfloat16* Bg = BT + (long)p*bpstride + (long)blockIdx.y*128*DD;
  const float* biasg = bias + (long)p*bias_pstride;

  __shared__ __align__(16) __hip_bfloat16 Asm[4][128*64];
  __shared__ __align__(16) __hip_bfloat16 Bsm[4][128*64];

  int tid = threadIdx.x;
  int w = tid>>6, lane = tid&63;
  int wr = w>>1, wc = w&1;
  int lr = lane>>4, lc = lane&15;
  int ldsbase = tid & ~63;

  // stage entire K=256 panel: 4 chunks x (4 A segs + 4 B segs) = 32 gld_lds
  #pragma unroll
  for (int c=0;c<4;c++){
    #pragma unroll
    for (int i=0;i<4;i++){
      int seg = i*256 + tid;
      int r = seg>>3, sl = seg&7;
      int sg = sl ^ (r&7);
      GLD_LDS16(Ag + (long)r*DD + c*64 + sg*8, &Asm[c][(i*256 + ldsbase)*8]);
      GLD_LDS16(Bg + (long)r*DD + c*64 + sg*8, &Bsm[c][(i*256 + ldsbase)*8]);
    }
  }
  asm volatile("s_waitcnt vmcnt(0)" ::: "memory");
  __syncthreads();

  f32x4 acc[4][4] = {};
  #pragma unroll
  for (int t=0;t<4;t++){
    #pragma unroll
    for (int kc=0;kc<2;kc++){
      bf16x8 af[4], bfr[4];
      #pragma unroll
      for (int mi=0;mi<4;mi++){
        int r = wr*64 + mi*16 + lc;
        int s = kc*4 + lr;
        af[mi] = *(const bf16x8*)(&Asm[t][r*64 + (s ^ (r&7))*8]);
      }
      #pragma unroll
      for (int ni=0;ni<4;ni++){
        int r = wc*64 + ni*16 + lc;
        int s = kc*4 + lr;
        bfr[ni] = *(const bf16x8*)(&Bsm[t][r*64 + (s ^ (r&7))*8]);
      }
      #pragma unroll
      for (int mi=0;mi<4;mi++)
        #pragma unroll
        for (int ni=0;ni<4;ni++)
          acc[mi][ni] = __builtin_amdgcn_mfma_f32_16x16x32_bf16(af[mi], bfr[ni], acc[mi][ni], 0, 0, 0);
    }
  }

  __hip_bfloat16* Cg = C + (long)g*cstride;
  #pragma unroll
  for (int ni=0;ni<4;ni++){
    int col = blockIdx.y*128 + wc*64 + ni*16 + lc;
    float bv = biasg[col];
    #pragma unroll
    for (int mi=0;mi<4;mi++){
      int row = blockIdx.x*128 + wr*64 + mi*16 + lr*4;
      #pragma unroll
      for (int j=0;j<4;j++){
        float v = acc[mi][ni][j] + bv;
        v = gelu_f(v);
        Cg[(long)(row+j)*ldc + col] = __float2bfloat16(v);
      }
    }
  }
}

// FF2 fused: 32x256 full-row tile, K=1024 (BK=64, dbuf). 512 blocks -> 2/CU.
template<bool LAST>
__global__ __launch_bounds__(256) void ff2_fused_kernel(
    const __hip_bfloat16* __restrict__ F,
    const __hip_bfloat16* __restrict__ w2l,
    const float* __restrict__ b2l,
    float* __restrict__ Xc,
    const float* __restrict__ g_ln,
    const float* __restrict__ b_ln,
    __hip_bfloat16* __restrict__ actOut,
    const int* __restrict__ cidx,
    const long long* __restrict__ psumsI,
    float* __restrict__ out)
{
  int rb = blockIdx.x;
  int g  = blockIdx.y;
  int p  = g & 3;
  const __hip_bfloat16* Ag = F + ((long)g*SS + rb*32)*FFD;
  const __hip_bfloat16* Bg = w2l + (long)p*((long)LL*DD*FFD);

  __shared__ __align__(16) __hip_bfloat16 As[2][32*64];
  __shared__ __align__(16) __hip_bfloat16 Bs[2][256*64];

  int tid = threadIdx.x;
  int w = tid>>6, lane = tid&63;
  int lr = lane>>4, lc = lane&15;
  int ldsbase = tid & ~63;

  const __hip_bfloat16* aseg;
  const __hip_bfloat16* bseg[8];
  {
    int seg = tid;
    int r = seg>>3, sl = seg&7;
    aseg = Ag + (long)r*FFD + (sl ^ (r&7))*8;
  }
  #pragma unroll
  for (int i=0;i<8;i++){
    int seg = i*256 + tid;
    int r = seg>>3, sl = seg&7;
    bseg[i] = Bg + (long)r*FFD + (sl ^ (r&7))*8;
  }

  f32x4 acc[2][4] = {};

  #define STAGE2(buf) do { \
    GLD_LDS16(aseg, &As[buf][ldsbase*8]); \
    _Pragma("unroll") \
    for (int i_=0;i_<8;i_++) \
      GLD_LDS16(bseg[i_], &Bs[buf][(i_*256 + ldsbase)*8]); \
    aseg += 64; \
    _Pragma("unroll") \
    for (int i_=0;i_<8;i_++) bseg[i_] += 64; \
  } while(0)

  STAGE2(0);
  asm volatile("s_waitcnt vmcnt(0)" ::: "memory");
  __syncthreads();

  for (int t=0; t<16; t++){
    int cur = t & 1;
    if (t+1 < 16) STAGE2(cur^1);
    #pragma unroll
    for (int kc=0;kc<2;kc++){
      bf16x8 af[2], bfr[4];
      #pragma unroll
      for (int mi=0;mi<2;mi++){
        int r = mi*16 + lc;
        int s = kc*4 + lr;
        af[mi] = *(const bf16x8*)(&As[cur][r*64 + (s ^ (r&7))*8]);
      }
      #pragma unroll
      for (int ni=0;ni<4;ni++){
        int c = w*64 + ni*16 + lc;
        int s = kc*4 + lr;
        bfr[ni] = *(const bf16x8*)(&Bs[cur][c*64 + (s ^ (c&7))*8]);
      }
      #pragma unroll
      for (int mi=0;mi<2;mi++)
        #pragma unroll
        for (int ni=0;ni<4;ni++)
          acc[mi][ni] = __builtin_amdgcn_mfma_f32_16x16x32_bf16(af[mi], bfr[ni], acc[mi][ni], 0, 0, 0);
    }
    if (t+1 < 16) asm volatile("s_waitcnt vmcnt(0)" ::: "memory");
    __syncthreads();
  }
  #undef STAGE2

  __syncthreads();
  float* pfl = (float*)&As[0][0];
  float* pfq = (float*)&As[0][0] + 128;
  float* Xg = Xc + (long)g*SS*DD + (long)rb*32*DD;

  float pwv = 1.0f;
  if (LAST){
    int b = g>>2;
    float ps[4];
    #pragma unroll
    for (int p2=0;p2<4;p2++)
      ps[p2] = (float)((double)psumsI[b*PP+p2] * (1.0/268435456.0/1024.0));
    float mxp = fmaxf(fmaxf(ps[0],ps[1]),fmaxf(ps[2],ps[3]));
    float e0=__expf(ps[0]-mxp), e1=__expf(ps[1]-mxp), e2=__expf(ps[2]-mxp), e3=__expf(ps[3]-mxp);
    float es = e0+e1+e2+e3;
    float ev = (p==0)?e0:(p==1)?e1:(p==2)?e2:e3;
    pwv = ev/es;
  }

  float srow[2][4], qrow[2][4];
  #pragma unroll
  for (int mi=0;mi<2;mi++)
    #pragma unroll
    for (int j=0;j<4;j++){ srow[mi][j]=0.f; qrow[mi][j]=0.f; }
  #pragma unroll
  for (int ni=0;ni<4;ni++){
    int col = w*64 + ni*16 + lc;
    float bv = b2l[p*(LL*DD) + col];
    #pragma unroll
    for (int mi=0;mi<2;mi++){
      int row = mi*16 + lr*4;
      #pragma unroll
      for (int j=0;j<4;j++){
        float v = Xg[(long)(row+j)*DD + col] + acc[mi][ni][j] + bv;
        if (!LAST) Xg[(long)(row+j)*DD + col] = v;
        if (LAST) v *= pwv;
        acc[mi][ni][j] = v;
        srow[mi][j] += v;
        qrow[mi][j] += v*v;
      }
    }
  }
  #pragma unroll
  for (int mi=0;mi<2;mi++)
    #pragma unroll
    for (int j=0;j<4;j++){
      float s2=srow[mi][j], q2=qrow[mi][j];
      s2 += __shfl_xor(s2,1); q2 += __shfl_xor(q2,1);
      s2 += __shfl_xor(s2,2); q2 += __shfl_xor(q2,2);
      s2 += __shfl_xor(s2,4); q2 += __shfl_xor(q2,4);
      s2 += __shfl_xor(s2,8); q2 += __shfl_xor(q2,8);
      srow[mi][j]=s2; qrow[mi][j]=q2;
    }
  if (lc==0){
    #pragma unroll
    for (int mi=0;mi<2;mi++)
      #pragma unroll
      for (int j=0;j<4;j++){
        int row = mi*16 + lr*4 + j;
        pfl[w*32+row] = srow[mi][j];
        pfq[w*32+row] = qrow[mi][j];
      }
  }
  __syncthreads();

  if (!LAST){
    __hip_bfloat16* Ya = actOut + ((long)g*SS + rb*32)*DD;
    const float* fg = g_ln + p*(LL*DD);
    const float* fb = b_ln + p*(LL*DD);
    #pragma unroll
    for (int mi=0;mi<2;mi++){
      #pragma unroll
      for (int j=0;j<4;j++){
        int row = mi*16 + lr*4 + j;
        float S = pfl[row] + pfl[32+row] + pfl[64+row] + pfl[96+row];
        float Q = pfq[row] + pfq[32+row] + pfq[64+row] + pfq[96+row];
        float mu = S*(1.0f/256.0f);
        float var = Q*(1.0f/256.0f) - mu*mu;
        float rs2 = rsqrtf(var + 1e-5f);
        #pragma unroll
        for (int ni=0;ni<4;ni++){
          int col = w*64 + ni*16 + lc;
          Ya[(long)row*DD + col] =
              __float2bfloat16((acc[mi][ni][j]-mu)*rs2*fg[col]+fb[col]);
        }
      }
    }
  } else {
    int b = g>>2;
    #pragma unroll
    for (int mi=0;mi<2;mi++){
      #pragma unroll
      for (int j=0;j<4;j++){
        int row = mi*16 + lr*4 + j;
        long slot = (long)g*SS + rb*32 + row;
        int i = cidx[slot];
        float S = pfl[row] + pfl[32+row] + pfl[64+row] + pfl[96+row];
        float Q = pfq[row] + pfq[32+row] + pfq[64+row] + pfq[96+row];
        float mu = S*(1.0f/256.0f);
        float var = Q*(1.0f/256.0f) - mu*mu;
        float rs2 = rsqrtf(var + 1e-5f);
        float* op = out + ((long)b*NN + i)*DD;
        #pragma unroll
        for (int ni=0;ni<4;ni++){
          int col = w*64 + ni*16 + lc;
          op[col] = (acc[mi][ni][j]-mu)*rs2*g_ln[col]+b_ln[col];
        }
      }
    }
  }
}

// K10: FUSED attention + fn-LayerNorm, 32-row tiles (grid (32,16) -> 2 blocks/CU)
__global__ __launch_bounds__(256) void fused_attn_kernel(
    const __hip_bfloat16* __restrict__ actA,
    const __hip_bfloat16* __restrict__ qk,
    const __hip_bfloat16* __restrict__ vwo,
    const float* __restrict__ wo_bl,
    const float* __restrict__ fn_gl,
    const float* __restrict__ fn_bl,
    float* __restrict__ Xc,
    __hip_bfloat16* __restrict__ actOut)
{
  int rb = blockIdx.x;
  int g  = blockIdx.y;
  int p  = g & 3;
  const __hip_bfloat16* Ag = actA + ((long)g*SS + rb*32)*DD;
  const __hip_bfloat16* Qg = qk  + (long)g*64*256;
  const __hip_bfloat16* Vg = vwo + (long)g*256*64;

  __shared__ __align__(16) __hip_bfloat16 sm[24576];
  int tid = threadIdx.x;
  int w = tid>>6, lane = tid&63;
  int lr = lane>>4, lc = lane&15;
  int ldsbase = tid & ~63;

  // Q: 64x256 at elem offset 8192 (32KB)
  #pragma unroll
  for (int i=0;i<8;i++){
    int seg = i*256 + tid;
    int r = seg>>5, sl = seg&31;
    int sg = sl ^ (r&7);
    GLD_LDS16(Qg + (long)r*256 + sg*8, &sm[8192 + (i*256 + ldsbase)*8]);
  }
  // A tile 0: 32x64 at elem offset 0 (4KB), dbuf at 2048
  {
    int r = tid>>3, sl = tid&7;
    int sg = sl ^ (r&7);
    GLD_LDS16(Ag + (long)r*DD + sg*8, &sm[0 + ldsbase*8]);
  }
  asm volatile("s_waitcnt vmcnt(0)" ::: "memory");
  __syncthreads();

  // QK^T: S = 32x64. Wave w: rows (w&1)*16, cols (w>>1)*32.
  f32x4 acc1[2] = {};
  for (int t=0; t<4; t++){
    int cur = t&1;
    if (t+1 < 4){
      int r = tid>>3, sl = tid&7;
      int sg = sl ^ (r&7);
      GLD_LDS16(Ag + (long)r*DD + (t+1)*64 + sg*8,
                &sm[(cur^1)*2048 + ldsbase*8]);
    }
    #pragma unroll
    for (int kc=0;kc<2;kc++){
      int r = (w&1)*16 + lc;
      int s = kc*4 + lr;
      bf16x8 af = *(const bf16x8*)(&sm[cur*2048 + r*64 + (s ^ (r&7))*8]);
      #pragma unroll
      for (int ni=0;ni<2;ni++){
        int rb_ = (w>>1)*32 + ni*16 + lc;
        int sb = t*8 + kc*4 + lr;
        bf16x8 bfr = *(const bf16x8*)(&sm[8192 + rb_*256 + (sb ^ (rb_&7))*8]);
        acc1[ni] = __builtin_amdgcn_mfma_f32_16x16x32_bf16(af, bfr, acc1[ni], 0, 0, 0);
      }
    }
    if (t+1 < 4) asm volatile("s_waitcnt vmcnt(0)" ::: "memory");
    __syncthreads();
  }

  // V: 256x64 at elem offset 8192 (32KB), overwrites Q
  #pragma unroll
  for (int i=0;i<8;i++){
    int seg = i*256 + tid;
    int r = seg>>3, sl = seg&7;
    int sg = sl ^ (r&7);
    GLD_LDS16(Vg + (long)r*64 + sg*8, &sm[8192 + (i*256 + ldsbase)*8]);
  }

  // softmax over each head's 8 kv (lanes differing in lc&7)
  float pv[2][4];
  #pragma unroll
  for (int ni=0;ni<2;ni++){
    #pragma unroll
    for (int j=0;j<4;j++){
      float v = acc1[ni][j];
      float mx = v;
      mx = fmaxf(mx, __shfl_xor(mx,1));
      mx = fmaxf(mx, __shfl_xor(mx,2));
      mx = fmaxf(mx, __shfl_xor(mx,4));
      float e = __expf(v - mx);
      float ssum = e;
      ssum += __shfl_xor(ssum,1);
      ssum += __shfl_xor(ssum,2);
      ssum += __shfl_xor(ssum,4);
      pv[ni][j] = e / ssum;
    }
  }
  // store P (32x64 bf16) at elem offset 0
  #pragma unroll
  for (int ni=0;ni<2;ni++){
    #pragma unroll
    for (int j=0;j<4;j++){
      int row = (w&1)*16 + lr*4 + j;
      int col = (w>>1)*32 + ni*16 + lc;
      int s = col>>3, e = col&7;
      sm[row*64 + ((s ^ (row&7))<<3) + e] = __float2bfloat16(pv[ni][j]);
    }
  }
  asm volatile("s_waitcnt vmcnt(0)" ::: "memory");
  __syncthreads();

  // PV: O = P(32x64) x V^T -> 32x256, waves split output cols (w*64)
  f32x4 acc2[2][4] = {};
  #pragma unroll
  for (int kc=0;kc<2;kc++){
    bf16x8 af[2], bfr[4];
    #pragma unroll
    for (int mi=0;mi<2;mi++){
      int r = mi*16 + lc;
      int s = kc*4 + lr;
      af[mi] = *(const bf16x8*)(&sm[r*64 + (s ^ (r&7))*8]);
    }
    #pragma unroll
    for (int ni=0;ni<4;ni++){
      int rb_ = w*64 + ni*16 + lc;
      int s = kc*4 + lr;
      bfr[ni] = *(const bf16x8*)(&sm[8192 + rb_*64 + (s ^ (rb_&7))*8]);
    }
    #pragma unroll
    for (int mi=0;mi<2;mi++)
      #pragma unroll
      for (int ni=0;ni<4;ni++)
        acc2[mi][ni] = __builtin_amdgcn_mfma_f32_16x16x32_bf16(af[mi], bfr[ni], acc2[mi][ni], 0, 0, 0);
  }

  __syncthreads();
  float* pfl = (float*)sm;
  float* pfq = (float*)sm + 128;
  float* Xg = Xc + (long)g*SS*DD + (long)rb*32*DD;
  float srow[2][4], qrow[2][4];
  #pragma unroll
  for (int mi=0;mi<2;mi++)
    #pragma unroll
    for (int j=0;j<4;j++){ srow[mi][j]=0.f; qrow[mi][j]=0.f; }
  #pragma unroll
  for (int ni=0;ni<4;ni++){
    int col = w*64 + ni*16 + lc;
    float bv = wo_bl[p*(LL*DD) + col];
    #pragma unroll
    for (int mi=0;mi<2;mi++){
      int row = mi*16 + lr*4;
      #pragma unroll
      for (int j=0;j<4;j++){
        float v = Xg[(long)(row+j)*DD + col] + acc2[mi][ni][j] + bv;
        Xg[(long)(row+j)*DD + col] = v;
        acc2[mi][ni][j] = v;
        srow[mi][j] += v;
        qrow[mi][j] += v*v;
      }
    }
  }
  #pragma unroll
  for (int mi=0;mi<2;mi++)
    #pragma unroll
    for (int j=0;j<4;j++){
      float s2=srow[mi][j], q2=qrow[mi][j];
      s2 += __shfl_xor(s2,1); q2 += __shfl_xor(q2,1);
      s2 += __shfl_xor(s2,2); q2 += __shfl_xor(q2,2);
      s2 += __shfl_xor(s2,4); q2 += __shfl_xor(q2,4);
      s2 += __shfl_xor(s2,8); q2 += __shfl_xor(q2,8);
      srow[mi][j]=s2; qrow[mi][j]=q2;
    }
  if (lc==0){
    #pragma unroll
    for (int mi=0;mi<2;mi++)
      #pragma unroll
      for (int j=0;j<4;j++){
        int row = mi*16 + lr*4 + j;
        pfl[w*32+row] = srow[mi][j];
        pfq[w*32+row] = qrow[mi][j];
      }
  }
  __syncthreads();
  __hip_bfloat16* Ya = actOut + ((long)g*SS + rb*32)*DD;
  const float* fg = fn_gl + p*(LL*DD);
  const float* fb = fn_bl + p*(LL*DD);
  #pragma unroll
  for (int mi=0;mi<2;mi++){
    #pragma unroll
    for (int j=0;j<4;j++){
      int row = mi*16 + lr*4 + j;
      float S = pfl[row] + pfl[32+row] + pfl[64+row] + pfl[96+row];
      float Q = pfq[row] + pfq[32+row] + pfq[64+row] + pfq[96+row];
      float mu = S*(1.0f/256.0f);
      float var = Q*(1.0f/256.0f) - mu*mu;
      float rs2 = rsqrtf(var + 1e-5f);
      #pragma unroll
      for (int ni=0;ni<4;ni++){
        int col = w*64 + ni*16 + lc;
        Ya[(long)row*DD + col] =
            __float2bfloat16((acc2[mi][ni][j]-mu)*rs2*fg[col]+fb[col]);
      }
    }
  }
}

extern "C" void kernel_launch(void* const* d_in, const int* in_sizes, int n_in,
                              void* d_out, int out_size, void* d_ws, size_t ws_size,
                              hipStream_t stream)
{
  (void)in_sizes; (void)n_in; (void)out_size; (void)ws_size;
  const float* x     =(const float*)d_in[0];
  const float* m     =(const float*)d_in[1];
  const float* proj_w=(const float*)d_in[2];
  const float* proj_b=(const float*)d_in[3];
  const float* lnp_g =(const float*)d_in[4];
  const float* lnp_b =(const float*)d_in[5];
  const float* sq_w  =(const float*)d_in[6];
  const float* sq_b  =(const float*)d_in[7];
  const float* sk_w  =(const float*)d_in[8];
  const float* sk_b  =(const float*)d_in[9];
  const float* sv_w  =(const float*)d_in[10];
  const float* sv_b  =(const float*)d_in[11];
  const float* an_g  =(const float*)d_in[12];
  const float* an_b  =(const float*)d_in[13];
  const float* wq    =(const float*)d_in[14];
  const float* wk    =(const float*)d_in[15];
  const float* wv    =(const float*)d_in[16];
  const float* wo    =(const float*)d_in[17];
  const float* wo_b  =(const float*)d_in[18];
  const float* fn_g  =(const float*)d_in[19];
  const float* fn_b  =(const float*)d_in[20];
  const float* w1    =(const float*)d_in[21];
  const float* b1    =(const float*)d_in[22];
  const float* w2    =(const float*)d_in[23];
  const float* b2    =(const float*)d_in[24];
  const float* fln_g =(const float*)d_in[25];
  const float* fln_b =(const float*)d_in[26];
  float* out = (float*)d_out;

  float* ws = (float*)d_ws;
  float* tokens  = ws;  ws += 4194304;  // 16 MB (start of actF 32MB span)
  ws += 4194304;                        // 16 MB actF second half
  float* Xc      = ws;  ws += 4194304;  // fp32 residual
  float* actAf   = ws;  ws += 2097152;  // bf16 16384x256
  float* wqTf    = ws;  ws += 524288;
  float* w1Tf    = ws;  ws += 1048576;
  float* w2Tf    = ws;  ws += 1048576;
  float* qkBf    = ws;  ws += 262144;   // bf16 [2][16][64][256]
  float* vwoTf   = ws;  ws += 262144;   // bf16 [2][16][256][64]
  float* kvk     = ws;  ws += 131072;
  float* kvv     = ws;  ws += 131072;
  float* kk2     = ws;  ws += 8192;
  float* kb      = ws;  ws += 32;
  float* vsc     = ws;  ws += 64;
  float* scores  = ws;  ws += 16384;
  long long* psumsI = (long long*)ws;  ws += 32;   // 16 x 8B
  int* rank      = (int*)ws;  ws += 16384;
  int* cidx      = (int*)ws;  ws += 16384;

  __hip_bfloat16* actA  = (__hip_bfloat16*)actAf;
  __hip_bfloat16* actF  = (__hip_bfloat16*)tokens;   // 16384x1024 bf16 span
  __hip_bfloat16* wqT   = (__hip_bfloat16*)wqTf;
  __hip_bfloat16* w1T   = (__hip_bfloat16*)w1Tf;
  __hip_bfloat16* w2T   = (__hip_bfloat16*)w2Tf;
  __hip_bfloat16* qkBuf = (__hip_bfloat16*)qkBf;
  __hip_bfloat16* vwoT  = (__hip_bfloat16*)vwoTf;

  scorer_kernel<<<32,256,0,stream>>>(m, sk_w, sk_b, sv_w, sv_b, sq_w, sq_b,
                                     kk2, kb, vsc);
  proj_prep_kernel<<<2560,256,0,stream>>>(
      x, proj_w, proj_b, lnp_g, lnp_b, kk2, kb, vsc,
      tokens, scores, rank, psumsI,
      m, an_g, an_b, wk, wv, kvk, kvv,
      wq, w1, w2, wqT, w1T, w2T);
  rank_qkvwo_kernel<<<1280,256,0,stream>>>(scores, rank, kvk, kvv, wqT, wo,
                                           qkBuf, vwoT);
  rank_finalize_kernel<<<64,256,0,stream>>>(rank, scores, cidx, psumsI);
  gather_ln_kernel<<<2048,256,0,stream>>>(tokens, cidx, Xc, actA, an_g, an_b);

  // layer 0
  fused_attn_kernel<<<dim3(32,16),256,0,stream>>>(
      actA, qkBuf, vwoT, wo_b, fn_g, fn_b, Xc, actA);
  ff1_gemm<<<dim3(8,8,16),256,0,stream>>>(
      actA, (long)SS*DD, w1T, (long)LL*FFD*DD,
      b1, LL*FFD, actF, FFD, (long)SS*FFD);
  ff2_fused_kernel<false><<<dim3(32,16),256,0,stream>>>(
      actF, w2T, b2, Xc, an_g + DD, an_b + DD, actA,
      nullptr, nullptr, nullptr);
  // layer 1
  fused_attn_kernel<<<dim3(32,16),256,0,stream>>>(
      actA, qkBuf + (long)16*64*256, vwoT + (long)16*256*64,
      wo_b + DD, fn_g + DD, fn_b + DD, Xc, actA);
  ff1_gemm<<<dim3(8,8,16),256,0,stream>>>(
      actA, (long)SS*DD, w1T + (long)FFD*DD, (long)LL*FFD*DD,
      b1 + FFD, LL*FFD, actF, FFD, (long)SS*FFD);
  ff2_fused_kernel<true><<<dim3(32,16),256,0,stream>>>(
      actF, w2T + (long)DD*FFD, b2 + DD, Xc, fln_g, fln_b, nullptr,
      cidx, psumsI, out);
}

// Round 33
// 216.714 us; speedup vs baseline: 1.0642x; 1.0642x over previous
//
#include <hip/hip_runtime.h>
#include <hip/hip_bf16.h>
#include <math.h>

// Problem constants
#define BB 4
#define CC 128
#define NN 4096      // H*W
#define DD 256
#define INNER 512
#define FFD 1024
#define PP 4
#define LL 2
#define NT 8
#define SS 1024      // NN/PP
#define SCALE 0.0625f // 1/sqrt(256)

typedef __attribute__((ext_vector_type(8))) short bf16x8;
typedef __attribute__((ext_vector_type(8))) short short8;
typedef __attribute__((ext_vector_type(4))) short short4v;
typedef __attribute__((ext_vector_type(4))) float f32x4;

#define GLD_LDS16(g, l) __builtin_amdgcn_global_load_lds( \
    (const __attribute__((address_space(1))) void*)(g), \
    (__attribute__((address_space(3))) void*)(l), 16, 0, 0)

template<int NW>
__device__ inline float block_sum(float v, float* sbuf){
  #pragma unroll
  for (int mk=32; mk; mk>>=1) v += __shfl_xor(v, mk);
  int w = threadIdx.x>>6;
  if ((threadIdx.x&63)==0) sbuf[w]=v;
  __syncthreads();
  float r = 0.f;
  #pragma unroll
  for (int k=0;k<NW;k++) r += sbuf[k];
  __syncthreads();
  return r;
}

__device__ inline unsigned short bf16bits(float v){
  __hip_bfloat16 t = __float2bfloat16(v);
  unsigned short u;
  __builtin_memcpy(&u, &t, 2);
  return u;
}
__device__ inline float bf2f(unsigned short u){
  unsigned int x = ((unsigned int)u)<<16;
  float f;
  __builtin_memcpy(&f, &x, 4);
  return f;
}

// fast GELU: erf via Abramowitz-Stegun 7.1.26 (|eps| <= 1.5e-7)
__device__ inline float gelu_f(float x){
  float z  = x * 0.70710678118654752440f;
  float az = fabsf(z);
  float t  = 1.0f / (1.0f + 0.3275911f*az);
  float y  = t*(0.254829592f + t*(-0.284496736f + t*(1.421413741f +
             t*(-1.453152027f + t*1.061405429f))));
  float erfv = 1.0f - y*__expf(-az*az);
  erfv = (z < 0.0f) ? -erfv : erfv;
  return 0.5f*x*(1.0f+erfv);
}

// K0: scorer (kk2/kb/vsc), 32 blocks
__global__ __launch_bounds__(256) void scorer_kernel(
    const float* __restrict__ m, const float* __restrict__ sk_w,
    const float* __restrict__ sk_b, const float* __restrict__ sv_w,
    const float* __restrict__ sv_b, const float* __restrict__ sq_w,
    const float* __restrict__ sq_b,
    float* __restrict__ kk2, float* __restrict__ kb, float* __restrict__ vsc)
{
  __shared__ float ms[256];
  __shared__ float ks[256];
  __shared__ float sbuf[4];
  int bj = blockIdx.x;
  int tid = threadIdx.x;
  ms[tid] = m[bj*DD + tid];
  __syncthreads();
  float acc=0.f;
  #pragma unroll 8
  for(int c=0;c<DD;c++) acc = fmaf(ms[c], sk_w[c*DD + tid], acc);
  ks[tid] = acc + sk_b[tid];
  float sv = block_sum<4>(ms[tid]*sv_w[tid], sbuf);
  if(tid==0) vsc[bj] = sv + sv_b[0];
  __syncthreads();
  const float* wr = sq_w + (long)tid*DD;
  float a2 = 0.f;
  #pragma unroll 4
  for (int c=0; c<DD; c+=4){
    float4 wvv = *(const float4*)(wr + c);
    a2 = fmaf(wvv.x, ks[c+0], fmaf(wvv.y, ks[c+1], fmaf(wvv.z, ks[c+2], fmaf(wvv.w, ks[c+3], a2))));
  }
  kk2[bj*DD + tid] = a2;
  float kbv = block_sum<4>(sq_b[tid]*ks[tid], sbuf);
  if (tid==0) kb[bj] = kbv;
}

// K1 MERGED, latency-bound work FIRST: [0,256) K/V; [256,1536) wconv;
// [1536,2560) proj+LN+scores. proj x reads are block-uniform -> scalar loads.
__global__ __launch_bounds__(256) void proj_prep_kernel(
    const float* __restrict__ x, const float* __restrict__ proj_w,
    const float* __restrict__ proj_b, const float* __restrict__ lnp_g,
    const float* __restrict__ lnp_b, const float* __restrict__ kk2,
    const float* __restrict__ kb, const float* __restrict__ vsc,
    float* __restrict__ tokens, float* __restrict__ scores,
    int* __restrict__ rank, long long* __restrict__ psumsI,
    const float* __restrict__ m, const float* __restrict__ an_g,
    const float* __restrict__ an_b, const float* __restrict__ wk,
    const float* __restrict__ wv, float* __restrict__ kvk,
    float* __restrict__ kvv,
    const float* __restrict__ wq, const float* __restrict__ w1,
    const float* __restrict__ w2,
    __hip_bfloat16* __restrict__ wqT, __hip_bfloat16* __restrict__ w1T,
    __hip_bfloat16* __restrict__ w2T)
{
  __shared__ union {
    struct {
      float ys[16][260];
      float kj[8][260];
      float kbs[8], vs[8], mu_s[16], rs_s[16];
      float lg[16][8];
    } pr;
    struct { float t[64][65]; } wc;
    struct { float mn[256]; float sbuf[4]; } kv;
  } sm;
  int z = blockIdx.x;
  int tid = threadIdx.x;

  if (z < 256){
    // ---- K/V precompute (latency-bound, dispatch first) ----
    float* mn = sm.kv.mn;
    float* sbuf = sm.kv.sbuf;
    int idx = z;
    int j = idx & 7, b = (idx>>3)&3, pl = idx>>5;
    float v = m[(b*NT+j)*DD + tid];
    float s = block_sum<4>(v, sbuf);
    float mu = s*(1.0f/256.0f);
    float dv = v-mu;
    float q = block_sum<4>(dv*dv, sbuf);
    float rs = rsqrtf(q*(1.0f/256.0f)+1e-5f);
    mn[tid] = dv*rs*an_g[pl*DD+tid] + an_b[pl*DD+tid];
    __syncthreads();
    float ka0=0.f, va0=0.f, ka1=0.f, va1=0.f;
    const float* wkb = wk + (long)pl*DD*INNER;
    const float* wvb = wv + (long)pl*DD*INNER;
    #pragma unroll 8
    for (int c=0;c<DD;c++){
      float mc = mn[c];
      const float* wkr = wkb + (long)c*INNER;
      const float* wvr = wvb + (long)c*INNER;
      ka0 = fmaf(mc, wkr[tid], ka0);
      ka1 = fmaf(mc, wkr[tid+256], ka1);
      va0 = fmaf(mc, wvr[tid], va0);
      va1 = fmaf(mc, wvr[tid+256], va1);
    }
    long off = ((long)pl*BB + b)*(NT*INNER) + j*INNER;
    kvk[off+tid]=ka0; kvk[off+tid+256]=ka1;
    kvv[off+tid]=va0; kvv[off+tid+256]=va1;
  } else if (z < 1536){
    // ---- weight convert+transpose (latency-bound) ----
    int z2 = z - 256;
    const float* src; __hip_bfloat16* dst; int K, N, rel;
    if (z2 < 256)      { src=wq; dst=wqT; K=DD;   N=INNER; rel=z2; }
    else if (z2 < 768) { src=w1; dst=w1T; K=DD;   N=FFD;   rel=z2-256; }
    else               { src=w2; dst=w2T; K=FFD;  N=DD;    rel=z2-768; }
    int tn = N>>6, tk = K>>6, per = tn*tk;
    int pl = rel/per, r2 = rel%per;
    int n0 = (r2%tn)*64, k0 = (r2/tn)*64;
    float (*t)[65] = sm.wc.t;
    #pragma unroll
    for (int i=0;i<4;i++){
      int idx = i*256+tid;
      int kk = idx>>4, n4 = idx&15;
      float4 v = *(const float4*)&src[((long)pl*K + k0+kk)*N + n0 + n4*4];
      t[kk][n4*4+0]=v.x; t[kk][n4*4+1]=v.y; t[kk][n4*4+2]=v.z; t[kk][n4*4+3]=v.w;
    }
    __syncthreads();
    #pragma unroll
    for (int i=0;i<4;i++){
      int idx = i*256+tid;
      int nn = idx>>4, k4 = idx&15;
      short4v o;
      o[0] = (short)bf16bits(t[k4*4+0][nn]);
      o[1] = (short)bf16bits(t[k4*4+1][nn]);
      o[2] = (short)bf16bits(t[k4*4+2][nn]);
      o[3] = (short)bf16bits(t[k4*4+3][nn]);
      *(short4v*)&dst[((long)pl*N + n0+nn)*K + k0 + k4*4] = o;
    }
  } else {
    // ---- proj + LN + scores (compute-bound, streams in behind prep) ----
    int zz = z - 1536;
    int b  = zz >> 8;
    int n0 = (zz & 255) * 16;
    if (tid < 16) rank[b*NN + n0 + tid] = 0;
    if (zz == 0 && tid < 16) psumsI[tid] = 0;
    float (*ys)[260] = sm.pr.ys;
    float (*kj)[260] = sm.pr.kj;
    float* kbs = sm.pr.kbs; float* vs = sm.pr.vs;
    float* mu_s = sm.pr.mu_s; float* rs_s = sm.pr.rs_s;
    float (*lg)[8] = sm.pr.lg;
    #pragma unroll
    for (int i=0;i<8;i++){
      int idx = i*256 + tid;
      int r = idx >> 8, c = idx & 255;
      kj[r][c] = kk2[(b*NT + r)*DD + c];
    }
    if (tid < 8){ kbs[tid] = kb[b*NT+tid]; vs[tid] = vsc[b*NT+tid]; }
    float acc[16];
    #pragma unroll
    for (int t=0;t<16;t++) acc[t]=0.f;
    const float* xb = x + (long)(b*CC)*NN + n0;
    for (int c0=0;c0<CC;c0+=4){
      float w0 = proj_w[(c0+0)*DD + tid];
      float w1_ = proj_w[(c0+1)*DD + tid];
      float w2_ = proj_w[(c0+2)*DD + tid];
      float w3_ = proj_w[(c0+3)*DD + tid];
      const float* x0 = xb + (long)(c0+0)*NN;
      const float* x1 = xb + (long)(c0+1)*NN;
      const float* x2 = xb + (long)(c0+2)*NN;
      const float* x3 = xb + (long)(c0+3)*NN;
      #pragma unroll
      for (int t=0;t<16;t++){
        acc[t] = fmaf(x0[t],w0,fmaf(x1[t],w1_,fmaf(x2[t],w2_,fmaf(x3[t],w3_,acc[t]))));
      }
    }
    float pb = proj_b[tid];
    #pragma unroll
    for (int t=0;t<16;t++) ys[t][tid] = acc[t] + pb;
    __syncthreads();
    int w = tid>>6, lane = tid&63;
    for (int k=0;k<4;k++){
      int t = w*4+k;
      float s = ys[t][lane] + ys[t][lane+64] + ys[t][lane+128] + ys[t][lane+192];
      #pragma unroll
      for (int mk=32; mk; mk>>=1) s += __shfl_xor(s, mk);
      float mu = s*(1.0f/256.0f);
      float d0=ys[t][lane]-mu, d1=ys[t][lane+64]-mu, d2=ys[t][lane+128]-mu, d3=ys[t][lane+192]-mu;
      float q = d0*d0+d1*d1+d2*d2+d3*d3;
      #pragma unroll
      for (int mk=32; mk; mk>>=1) q += __shfl_xor(q, mk);
      if (lane==0){ mu_s[t]=mu; rs_s[t]=rsqrtf(q*(1.0f/256.0f)+1e-5f); }
    }
    __syncthreads();
    float g = lnp_g[tid], be = lnp_b[tid];
    #pragma unroll
    for (int t=0;t<16;t++){
      float nv = (ys[t][tid]-mu_s[t])*rs_s[t]*g + be;
      tokens[((long)(b*NN + n0 + t))*DD + tid] = nv;
      ys[t][tid] = nv;
    }
    __syncthreads();
    if (tid < 128){
      int t = tid>>3, j = tid&7;
      float a2 = 0.f;
      for (int c0=0;c0<DD;c0+=4){
        float4 tv = *(const float4*)&ys[t][c0];
        float4 kv2 = *(const float4*)&kj[j][c0];
        a2 = fmaf(tv.x,kv2.x,fmaf(tv.y,kv2.y,fmaf(tv.z,kv2.z,fmaf(tv.w,kv2.w,a2))));
      }
      lg[t][j] = (a2 + kbs[j]) * SCALE;
    }
    __syncthreads();
    if (tid < 16){
      float mx=-1e30f;
      #pragma unroll
      for(int j=0;j<NT;j++) mx=fmaxf(mx,lg[tid][j]);
      float s=0.f, sc=0.f;
      #pragma unroll
      for(int j=0;j<NT;j++){ float e=__expf(lg[tid][j]-mx); s+=e; sc+=e*vs[j]; }
      scores[b*NN + n0 + tid] = sc/s;
    }
  }
}

// K2 MERGED: blocks [0,256) qkvwo (first, depends only on kvk/kvv/wqT);
// [256,1280) partial ranks
__global__ __launch_bounds__(256) void rank_qkvwo_kernel(
    const float* __restrict__ scores, int* __restrict__ rank,
    const float* __restrict__ kvk, const float* __restrict__ kvv,
    const __hip_bfloat16* __restrict__ wqT, const float* __restrict__ wo,
    __hip_bfloat16* __restrict__ qkBuf, __hip_bfloat16* __restrict__ vwoT)
{
  __shared__ union {
    struct { float ss[256]; } rk;
    struct { float kL[8][64]; float vL[8][64]; } qv;
  } sm;
  int z = blockIdx.x;
  if (z >= 256){
    int zz = z - 256;
    int b  = zz >> 8;
    int it = (zz >> 4) & 15;
    int jt = zz & 15;
    int i = it*256 + threadIdx.x;
    float si = scores[b*NN + i];
    sm.rk.ss[threadIdx.x] = scores[b*NN + jt*256 + threadIdx.x];
    __syncthreads();
    int jbase = jt*256;
    int cnt = 0;
    #pragma unroll 4
    for (int j=0;j<256;j++){
      float sj = sm.rk.ss[j];
      cnt += (sj > si) || (sj == si && (jbase+j) < i);
    }
    atomicAdd(&rank[b*NN+i], cnt);
  } else {
    int zz = z;                      // z*8 + h
    int z3 = zz>>3, h = zz&7;
    int l = z3>>4, g = z3&15;
    int b = g>>2, p = g&3;
    int pl = p*LL + l;
    int c = threadIdx.x;
    float (*kL)[64] = sm.qv.kL;
    float (*vL)[64] = sm.qv.vL;
    {
      int j0 = c>>6, d0 = c&63;
      long off = ((long)pl*BB + b)*(NT*INNER) + h*64 + d0;
      kL[j0][d0]   = kvk[off + j0*INNER];
      vL[j0][d0]   = kvv[off + j0*INNER];
      kL[j0+4][d0] = kvk[off + (j0+4)*INNER];
      vL[j0+4][d0] = kvv[off + (j0+4)*INNER];
    }
    __syncthreads();
    float qa[8] = {0,0,0,0,0,0,0,0};
    float va[8] = {0,0,0,0,0,0,0,0};
    const __hip_bfloat16* wqp = wqT + ((long)pl*INNER + h*64)*DD + c;
    const float* wop = wo + ((long)pl*INNER + h*64)*DD + c;
    #pragma unroll 4
    for (int d=0; d<64; d++){
      float wqv = bf2f(*(const unsigned short*)(wqp + (long)d*DD));
      float wov = wop[(long)d*DD];
      #pragma unroll
      for (int j=0;j<8;j++){
        qa[j] = fmaf(kL[j][d], wqv, qa[j]);
        va[j] = fmaf(vL[j][d], wov, va[j]);
      }
    }
    __hip_bfloat16* qkg = qkBuf + (long)z3*64*256;
    __hip_bfloat16* vwg = vwoT + (long)z3*256*64;
    #pragma unroll
    for (int j=0;j<8;j++)
      qkg[(h*8+j)*256 + c] = __float2bfloat16(qa[j]*SCALE);
    short8 o;
    #pragma unroll
    for (int j=0;j<8;j++) o[j] = (short)bf16bits(va[j]);
    *(short8*)(vwg + c*64 + h*8) = o;
  }
}

// K3b: cidx + fixed-point partition score sums (hierarchical, deterministic)
__global__ __launch_bounds__(256) void rank_finalize_kernel(
    const int* __restrict__ rank, const float* __restrict__ scores,
    int* __restrict__ cidx, long long* __restrict__ psumsI)
{
  __shared__ unsigned long long bins[PP];
  if (threadIdx.x < PP) bins[threadIdx.x] = 0ull;
  __syncthreads();
  int b = blockIdx.x >> 4;
  int i = (blockIdx.x & 15)*256 + threadIdx.x;
  int rk = rank[b*NN + i];
  int p = rk >> 10;
  cidx[(b*PP + p)*SS + (rk & (SS-1))] = i;
  long long iv = (long long)llrintf(scores[b*NN + i] * 268435456.0f); // 2^28
  atomicAdd(&bins[p], (unsigned long long)iv);
  __syncthreads();
  if (threadIdx.x < PP)
    atomicAdd((unsigned long long*)&psumsI[b*PP + threadIdx.x], bins[threadIdx.x]);
}

// K6: gather + LN(an[p,0]) fused
__global__ __launch_bounds__(256) void gather_ln_kernel(
    const float* __restrict__ tokens, const int* __restrict__ cidx,
    float* __restrict__ Xc, __hip_bfloat16* __restrict__ Y,
    const float* __restrict__ gamma, const float* __restrict__ beta)
{
  long slot = (long)blockIdx.x*8 + (threadIdx.x>>5);
  int l32 = threadIdx.x & 31;
  int b = (int)(slot >> 12);
  int p = (int)((slot>>10)&3);
  int i = cidx[slot];
  const float* src = tokens + ((long)b*NN + i)*DD + l32*8;
  float4 v0 = *(const float4*)src;
  float4 v1 = *(const float4*)(src+4);
  *(float4*)(Xc + slot*DD + l32*8) = v0;
  *(float4*)(Xc + slot*DD + l32*8 + 4) = v1;
  float s = v0.x+v0.y+v0.z+v0.w+v1.x+v1.y+v1.z+v1.w;
  #pragma unroll
  for (int mk=16; mk; mk>>=1) s += __shfl_xor(s, mk);
  float mu = s*(1.0f/256.0f);
  float vv[8] = {v0.x,v0.y,v0.z,v0.w,v1.x,v1.y,v1.z,v1.w};
  float q = 0.f;
  #pragma unroll
  for (int k=0;k<8;k++){ float d = vv[k]-mu; q += d*d; }
  #pragma unroll
  for (int mk=16; mk; mk>>=1) q += __shfl_xor(q, mk);
  float rs = rsqrtf(q*(1.0f/256.0f)+1e-5f);
  short8 o;
  #pragma unroll
  for (int k=0;k<8;k++){
    int d = l32*8+k;
    o[k] = (short)bf16bits((vv[k]-mu)*rs*gamma[p*(LL*DD)+d]+beta[p*(LL*DD)+d]);
  }
  *(short8*)(Y + slot*DD + l32*8) = o;
}

// K9: FF1 GEMM, 128x64 tile, K=256 (BK=64, dbuf). LDS 48KB -> 3 blocks/CU.
// Grid (8,16,16) = 2048 blocks. Same K accumulation order as before.
__global__ __launch_bounds__(256) void ff1_gemm(
    const __hip_bfloat16* __restrict__ A, long astride,
    const __hip_bfloat16* __restrict__ BT, long bpstride,
    const float* __restrict__ bias, int bias_pstride,
    __hip_bfloat16* __restrict__ C, int ldc, long cstride)
{
  int g = blockIdx.z;
  int p = g & 3;
  const __hip_bfloat16* Ag = A  + (long)g*astride + (long)blockIdx.x*128*DD;
  const __hip_bfloat16* Bg = BT + (long)p*bpstride + (long)blockIdx.y*64*DD;
  const float* biasg = bias + (long)p*bias_pstride;

  __shared__ __align__(16) __hip_bfloat16 Asm[2][128*64];
  __shared__ __align__(16) __hip_bfloat16 Bsm[2][64*64];

  int tid = threadIdx.x;
  int w = tid>>6, lane = tid&63;
  int lr = lane>>4, lc = lane&15;
  int ldsbase = tid & ~63;

  const __hip_bfloat16* aseg[4];
  const __hip_bfloat16* bseg[2];
  #pragma unroll
  for (int i=0;i<4;i++){
    int seg = i*256 + tid;
    int r = seg>>3, sl = seg&7;
    aseg[i] = Ag + (long)r*DD + (sl ^ (r&7))*8;
  }
  #pragma unroll
  for (int i=0;i<2;i++){
    int seg = i*256 + tid;
    int r = seg>>3, sl = seg&7;
    bseg[i] = Bg + (long)r*DD + (sl ^ (r&7))*8;
  }

  f32x4 acc[2][4] = {};

  #define STAGE1(buf) do { \
    _Pragma("unroll") \
    for (int i_=0;i_<4;i_++) \
      GLD_LDS16(aseg[i_], &Asm[buf][(i_*256 + ldsbase)*8]); \
    _Pragma("unroll") \
    for (int i_=0;i_<2;i_++) \
      GLD_LDS16(bseg[i_], &Bsm[buf][(i_*256 + ldsbase)*8]); \
    _Pragma("unroll") \
    for (int i_=0;i_<4;i_++) aseg[i_] += 64; \
    _Pragma("unroll") \
    for (int i_=0;i_<2;i_++) bseg[i_] += 64; \
  } while(0)

  STAGE1(0);
  asm volatile("s_waitcnt vmcnt(0)" ::: "memory");
  __syncthreads();

  for (int t=0; t<4; t++){
    int cur = t & 1;
    if (t+1 < 4) STAGE1(cur^1);
    #pragma unroll
    for (int kc=0;kc<2;kc++){
      bf16x8 af[2], bfr[4];
      #pragma unroll
      for (int mi=0;mi<2;mi++){
        int r = w*32 + mi*16 + lc;
        int s = kc*4 + lr;
        af[mi] = *(const bf16x8*)(&Asm[cur][r*64 + (s ^ (r&7))*8]);
      }
      #pragma unroll
      for (int ni=0;ni<4;ni++){
        int r = ni*16 + lc;
        int s = kc*4 + lr;
        bfr[ni] = *(const bf16x8*)(&Bsm[cur][r*64 + (s ^ (r&7))*8]);
      }
      #pragma unroll
      for (int mi=0;mi<2;mi++)
        #pragma unroll
        for (int ni=0;ni<4;ni++)
          acc[mi][ni] = __builtin_amdgcn_mfma_f32_16x16x32_bf16(af[mi], bfr[ni], acc[mi][ni], 0, 0, 0);
    }
    if (t+1 < 4) asm volatile("s_waitcnt vmcnt(0)" ::: "memory");
    __syncthreads();
  }
  #undef STAGE1

  __hip_bfloat16* Cg = C + (long)g*cstride;
  #pragma unroll
  for (int ni=0;ni<4;ni++){
    int col = blockIdx.y*64 + ni*16 + lc;
    float bv = biasg[col];
    #pragma unroll
    for (int mi=0;mi<2;mi++){
      int row = blockIdx.x*128 + w*32 + mi*16 + lr*4;
      #pragma unroll
      for (int j=0;j<4;j++){
        float v = acc[mi][ni][j] + bv;
        v = gelu_f(v);
        Cg[(long)(row+j)*ldc + col] = __float2bfloat16(v);
      }
    }
  }
}

// FF2 fused: 32x256 full-row tile, K=1024 (BK=64, dbuf). 512 blocks -> 2/CU.
template<bool LAST>
__global__ __launch_bounds__(256) void ff2_fused_kernel(
    const __hip_bfloat16* __restrict__ F,
    const __hip_bfloat16* __restrict__ w2l,
    const float* __restrict__ b2l,
    float* __restrict__ Xc,
    const float* __restrict__ g_ln,
    const float* __restrict__ b_ln,
    __hip_bfloat16* __restrict__ actOut,
    const int* __restrict__ cidx,
    const long long* __restrict__ psumsI,
    float* __restrict__ out)
{
  int rb = blockIdx.x;
  int g  = blockIdx.y;
  int p  = g & 3;
  const __hip_bfloat16* Ag = F + ((long)g*SS + rb*32)*FFD;
  const __hip_bfloat16* Bg = w2l + (long)p*((long)LL*DD*FFD);

  __shared__ __align__(16) __hip_bfloat16 As[2][32*64];
  __shared__ __align__(16) __hip_bfloat16 Bs[2][256*64];

  int tid = threadIdx.x;
  int w = tid>>6, lane = tid&63;
  int lr = lane>>4, lc = lane&15;
  int ldsbase = tid & ~63;

  const __hip_bfloat16* aseg;
  const __hip_bfloat16* bseg[8];
  {
    int seg = tid;
    int r = seg>>3, sl = seg&7;
    aseg = Ag + (long)r*FFD + (sl ^ (r&7))*8;
  }
  #pragma unroll
  for (int i=0;i<8;i++){
    int seg = i*256 + tid;
    int r = seg>>3, sl = seg&7;
    bseg[i] = Bg + (long)r*FFD + (sl ^ (r&7))*8;
  }

  f32x4 acc[2][4] = {};

  #define STAGE2(buf) do { \
    GLD_LDS16(aseg, &As[buf][ldsbase*8]); \
    _Pragma("unroll") \
    for (int i_=0;i_<8;i_++) \
      GLD_LDS16(bseg[i_], &Bs[buf][(i_*256 + ldsbase)*8]); \
    aseg += 64; \
    _Pragma("unroll") \
    for (int i_=0;i_<8;i_++) bseg[i_] += 64; \
  } while(0)

  STAGE2(0);
  asm volatile("s_waitcnt vmcnt(0)" ::: "memory");
  __syncthreads();

  for (int t=0; t<16; t++){
    int cur = t & 1;
    if (t+1 < 16) STAGE2(cur^1);
    #pragma unroll
    for (int kc=0;kc<2;kc++){
      bf16x8 af[2], bfr[4];
      #pragma unroll
      for (int mi=0;mi<2;mi++){
        int r = mi*16 + lc;
        int s = kc*4 + lr;
        af[mi] = *(const bf16x8*)(&As[cur][r*64 + (s ^ (r&7))*8]);
      }
      #pragma unroll
      for (int ni=0;ni<4;ni++){
        int c = w*64 + ni*16 + lc;
        int s = kc*4 + lr;
        bfr[ni] = *(const bf16x8*)(&Bs[cur][c*64 + (s ^ (c&7))*8]);
      }
      #pragma unroll
      for (int mi=0;mi<2;mi++)
        #pragma unroll
        for (int ni=0;ni<4;ni++)
          acc[mi][ni] = __builtin_amdgcn_mfma_f32_16x16x32_bf16(af[mi], bfr[ni], acc[mi][ni], 0, 0, 0);
    }
    if (t+1 < 16) asm volatile("s_waitcnt vmcnt(0)" ::: "memory");
    __syncthreads();
  }
  #undef STAGE2

  __syncthreads();
  float* pfl = (float*)&As[0][0];
  float* pfq = (float*)&As[0][0] + 128;
  float* Xg = Xc + (long)g*SS*DD + (long)rb*32*DD;

  float pwv = 1.0f;
  if (LAST){
    int b = g>>2;
    float ps[4];
    #pragma unroll
    for (int p2=0;p2<4;p2++)
      ps[p2] = (float)((double)psumsI[b*PP+p2] * (1.0/268435456.0/1024.0));
    float mxp = fmaxf(fmaxf(ps[0],ps[1]),fmaxf(ps[2],ps[3]));
    float e0=__expf(ps[0]-mxp), e1=__expf(ps[1]-mxp), e2=__expf(ps[2]-mxp), e3=__expf(ps[3]-mxp);
    float es = e0+e1+e2+e3;
    float ev = (p==0)?e0:(p==1)?e1:(p==2)?e2:e3;
    pwv = ev/es;
  }

  float srow[2][4], qrow[2][4];
  #pragma unroll
  for (int mi=0;mi<2;mi++)
    #pragma unroll
    for (int j=0;j<4;j++){ srow[mi][j]=0.f; qrow[mi][j]=0.f; }
  #pragma unroll
  for (int ni=0;ni<4;ni++){
    int col = w*64 + ni*16 + lc;
    float bv = b2l[p*(LL*DD) + col];
    #pragma unroll
    for (int mi=0;mi<2;mi++){
      int row = mi*16 + lr*4;
      #pragma unroll
      for (int j=0;j<4;j++){
        float v = Xg[(long)(row+j)*DD + col] + acc[mi][ni][j] + bv;
        if (!LAST) Xg[(long)(row+j)*DD + col] = v;
        if (LAST) v *= pwv;
        acc[mi][ni][j] = v;
        srow[mi][j] += v;
        qrow[mi][j] += v*v;
      }
    }
  }
  #pragma unroll
  for (int mi=0;mi<2;mi++)
    #pragma unroll
    for (int j=0;j<4;j++){
      float s2=srow[mi][j], q2=qrow[mi][j];
      s2 += __shfl_xor(s2,1); q2 += __shfl_xor(q2,1);
      s2 += __shfl_xor(s2,2); q2 += __shfl_xor(q2,2);
      s2 += __shfl_xor(s2,4); q2 += __shfl_xor(q2,4);
      s2 += __shfl_xor(s2,8); q2 += __shfl_xor(q2,8);
      srow[mi][j]=s2; qrow[mi][j]=q2;
    }
  if (lc==0){
    #pragma unroll
    for (int mi=0;mi<2;mi++)
      #pragma unroll
      for (int j=0;j<4;j++){
        int row = mi*16 + lr*4 + j;
        pfl[w*32+row] = srow[mi][j];
        pfq[w*32+row] = qrow[mi][j];
      }
  }
  __syncthreads();

  if (!LAST){
    __hip_bfloat16* Ya = actOut + ((long)g*SS + rb*32)*DD;
    const float* fg = g_ln + p*(LL*DD);
    const float* fb = b_ln + p*(LL*DD);
    #pragma unroll
    for (int mi=0;mi<2;mi++){
      #pragma unroll
      for (int j=0;j<4;j++){
        int row = mi*16 + lr*4 + j;
        float S = pfl[row] + pfl[32+row] + pfl[64+row] + pfl[96+row];
        float Q = pfq[row] + pfq[32+row] + pfq[64+row] + pfq[96+row];
        float mu = S*(1.0f/256.0f);
        float var = Q*(1.0f/256.0f) - mu*mu;
        float rs2 = rsqrtf(var + 1e-5f);
        #pragma unroll
        for (int ni=0;ni<4;ni++){
          int col = w*64 + ni*16 + lc;
          Ya[(long)row*DD + col] =
              __float2bfloat16((acc[mi][ni][j]-mu)*rs2*fg[col]+fb[col]);
        }
      }
    }
  } else {
    int b = g>>2;
    #pragma unroll
    for (int mi=0;mi<2;mi++){
      #pragma unroll
      for (int j=0;j<4;j++){
        int row = mi*16 + lr*4 + j;
        long slot = (long)g*SS + rb*32 + row;
        int i = cidx[slot];
        float S = pfl[row] + pfl[32+row] + pfl[64+row] + pfl[96+row];
        float Q = pfq[row] + pfq[32+row] + pfq[64+row] + pfq[96+row];
        float mu = S*(1.0f/256.0f);
        float var = Q*(1.0f/256.0f) - mu*mu;
        float rs2 = rsqrtf(var + 1e-5f);
        float* op = out + ((long)b*NN + i)*DD;
        #pragma unroll
        for (int ni=0;ni<4;ni++){
          int col = w*64 + ni*16 + lc;
          op[col] = (acc[mi][ni][j]-mu)*rs2*g_ln[col]+b_ln[col];
        }
      }
    }
  }
}

// K10: FUSED attention + fn-LayerNorm, 32-row tiles (grid (32,16) -> 2 blocks/CU)
__global__ __launch_bounds__(256) void fused_attn_kernel(
    const __hip_bfloat16* __restrict__ actA,
    const __hip_bfloat16* __restrict__ qk,
    const __hip_bfloat16* __restrict__ vwo,
    const float* __restrict__ wo_bl,
    const float* __restrict__ fn_gl,
    const float* __restrict__ fn_bl,
    float* __restrict__ Xc,
    __hip_bfloat16* __restrict__ actOut)
{
  int rb = blockIdx.x;
  int g  = blockIdx.y;
  int p  = g & 3;
  const __hip_bfloat16* Ag = actA + ((long)g*SS + rb*32)*DD;
  const __hip_bfloat16* Qg = qk  + (long)g*64*256;
  const __hip_bfloat16* Vg = vwo + (long)g*256*64;

  __shared__ __align__(16) __hip_bfloat16 sm[24576];
  int tid = threadIdx.x;
  int w = tid>>6, lane = tid&63;
  int lr = lane>>4, lc = lane&15;
  int ldsbase = tid & ~63;

  // Q: 64x256 at elem offset 8192 (32KB)
  #pragma unroll
  for (int i=0;i<8;i++){
    int seg = i*256 + tid;
    int r = seg>>5, sl = seg&31;
    int sg = sl ^ (r&7);
    GLD_LDS16(Qg + (long)r*256 + sg*8, &sm[8192 + (i*256 + ldsbase)*8]);
  }
  // A tile 0: 32x64 at elem offset 0 (4KB), dbuf at 2048
  {
    int r = tid>>3, sl = tid&7;
    int sg = sl ^ (r&7);
    GLD_LDS16(Ag + (long)r*DD + sg*8, &sm[0 + ldsbase*8]);
  }
  asm volatile("s_waitcnt vmcnt(0)" ::: "memory");
  __syncthreads();

  // QK^T: S = 32x64. Wave w: rows (w&1)*16, cols (w>>1)*32.
  f32x4 acc1[2] = {};
  for (int t=0; t<4; t++){
    int cur = t&1;
    if (t+1 < 4){
      int r = tid>>3, sl = tid&7;
      int sg = sl ^ (r&7);
      GLD_LDS16(Ag + (long)r*DD + (t+1)*64 + sg*8,
                &sm[(cur^1)*2048 + ldsbase*8]);
    }
    #pragma unroll
    for (int kc=0;kc<2;kc++){
      int r = (w&1)*16 + lc;
      int s = kc*4 + lr;
      bf16x8 af = *(const bf16x8*)(&sm[cur*2048 + r*64 + (s ^ (r&7))*8]);
      #pragma unroll
      for (int ni=0;ni<2;ni++){
        int rb_ = (w>>1)*32 + ni*16 + lc;
        int sb = t*8 + kc*4 + lr;
        bf16x8 bfr = *(const bf16x8*)(&sm[8192 + rb_*256 + (sb ^ (rb_&7))*8]);
        acc1[ni] = __builtin_amdgcn_mfma_f32_16x16x32_bf16(af, bfr, acc1[ni], 0, 0, 0);
      }
    }
    if (t+1 < 4) asm volatile("s_waitcnt vmcnt(0)" ::: "memory");
    __syncthreads();
  }

  // V: 256x64 at elem offset 8192 (32KB), overwrites Q
  #pragma unroll
  for (int i=0;i<8;i++){
    int seg = i*256 + tid;
    int r = seg>>3, sl = seg&7;
    int sg = sl ^ (r&7);
    GLD_LDS16(Vg + (long)r*64 + sg*8, &sm[8192 + (i*256 + ldsbase)*8]);
  }

  // softmax over each head's 8 kv (lanes differing in lc&7)
  float pv[2][4];
  #pragma unroll
  for (int ni=0;ni<2;ni++){
    #pragma unroll
    for (int j=0;j<4;j++){
      float v = acc1[ni][j];
      float mx = v;
      mx = fmaxf(mx, __shfl_xor(mx,1));
      mx = fmaxf(mx, __shfl_xor(mx,2));
      mx = fmaxf(mx, __shfl_xor(mx,4));
      float e = __expf(v - mx);
      float ssum = e;
      ssum += __shfl_xor(ssum,1);
      ssum += __shfl_xor(ssum,2);
      ssum += __shfl_xor(ssum,4);
      pv[ni][j] = e / ssum;
    }
  }
  // store P (32x64 bf16) at elem offset 0
  #pragma unroll
  for (int ni=0;ni<2;ni++){
    #pragma unroll
    for (int j=0;j<4;j++){
      int row = (w&1)*16 + lr*4 + j;
      int col = (w>>1)*32 + ni*16 + lc;
      int s = col>>3, e = col&7;
      sm[row*64 + ((s ^ (row&7))<<3) + e] = __float2bfloat16(pv[ni][j]);
    }
  }
  asm volatile("s_waitcnt vmcnt(0)" ::: "memory");
  __syncthreads();

  // PV: O = P(32x64) x V^T -> 32x256, waves split output cols (w*64)
  f32x4 acc2[2][4] = {};
  #pragma unroll
  for (int kc=0;kc<2;kc++){
    bf16x8 af[2], bfr[4];
    #pragma unroll
    for (int mi=0;mi<2;mi++){
      int r = mi*16 + lc;
      int s = kc*4 + lr;
      af[mi] = *(const bf16x8*)(&sm[r*64 + (s ^ (r&7))*8]);
    }
    #pragma unroll
    for (int ni=0;ni<4;ni++){
      int rb_ = w*64 + ni*16 + lc;
      int s = kc*4 + lr;
      bfr[ni] = *(const bf16x8*)(&sm[8192 + rb_*64 + (s ^ (rb_&7))*8]);
    }
    #pragma unroll
    for (int mi=0;mi<2;mi++)
      #pragma unroll
      for (int ni=0;ni<4;ni++)
        acc2[mi][ni] = __builtin_amdgcn_mfma_f32_16x16x32_bf16(af[mi], bfr[ni], acc2[mi][ni], 0, 0, 0);
  }

  __syncthreads();
  float* pfl = (float*)sm;
  float* pfq = (float*)sm + 128;
  float* Xg = Xc + (long)g*SS*DD + (long)rb*32*DD;
  float srow[2][4], qrow[2][4];
  #pragma unroll
  for (int mi=0;mi<2;mi++)
    #pragma unroll
    for (int j=0;j<4;j++){ srow[mi][j]=0.f; qrow[mi][j]=0.f; }
  #pragma unroll
  for (int ni=0;ni<4;ni++){
    int col = w*64 + ni*16 + lc;
    float bv = wo_bl[p*(LL*DD) + col];
    #pragma unroll
    for (int mi=0;mi<2;mi++){
      int row = mi*16 + lr*4;
      #pragma unroll
      for (int j=0;j<4;j++){
        float v = Xg[(long)(row+j)*DD + col] + acc2[mi][ni][j] + bv;
        Xg[(long)(row+j)*DD + col] = v;
        acc2[mi][ni][j] = v;
        srow[mi][j] += v;
        qrow[mi][j] += v*v;
      }
    }
  }
  #pragma unroll
  for (int mi=0;mi<2;mi++)
    #pragma unroll
    for (int j=0;j<4;j++){
      float s2=srow[mi][j], q2=qrow[mi][j];
      s2 += __shfl_xor(s2,1); q2 += __shfl_xor(q2,1);
      s2 += __shfl_xor(s2,2); q2 += __shfl_xor(q2,2);
      s2 += __shfl_xor(s2,4); q2 += __shfl_xor(q2,4);
      s2 += __shfl_xor(s2,8); q2 += __shfl_xor(q2,8);
      srow[mi][j]=s2; qrow[mi][j]=q2;
    }
  if (lc==0){
    #pragma unroll
    for (int mi=0;mi<2;mi++)
      #pragma unroll
      for (int j=0;j<4;j++){
        int row = mi*16 + lr*4 + j;
        pfl[w*32+row] = srow[mi][j];
        pfq[w*32+row] = qrow[mi][j];
      }
  }
  __syncthreads();
  __hip_bfloat16* Ya = actOut + ((long)g*SS + rb*32)*DD;
  const float* fg = fn_gl + p*(LL*DD);
  const float* fb = fn_bl + p*(LL*DD);
  #pragma unroll
  for (int mi=0;mi<2;mi++){
    #pragma unroll
    for (int j=0;j<4;j++){
      int row = mi*16 + lr*4 + j;
      float S = pfl[row] + pfl[32+row] + pfl[64+row] + pfl[96+row];
      float Q = pfq[row] + pfq[32+row] + pfq[64+row] + pfq[96+row];
      float mu = S*(1.0f/256.0f);
      float var = Q*(1.0f/256.0f) - mu*mu;
      float rs2 = rsqrtf(var + 1e-5f);
      #pragma unroll
      for (int ni=0;ni<4;ni++){
        int col = w*64 + ni*16 + lc;
        Ya[(long)row*DD + col] =
            __float2bfloat16((acc2[mi][ni][j]-mu)*rs2*fg[col]+fb[col]);
      }
    }
  }
}

extern "C" void kernel_launch(void* const* d_in, const int* in_sizes, int n_in,
                              void* d_out, int out_size, void* d_ws, size_t ws_size,
                              hipStream_t stream)
{
  (void)in_sizes; (void)n_in; (void)out_size; (void)ws_size;
  const float* x     =(const float*)d_in[0];
  const float* m     =(const float*)d_in[1];
  const float* proj_w=(const float*)d_in[2];
  const float* proj_b=(const float*)d_in[3];
  const float* lnp_g =(const float*)d_in[4];
  const float* lnp_b =(const float*)d_in[5];
  const float* sq_w  =(const float*)d_in[6];
  const float* sq_b  =(const float*)d_in[7];
  const float* sk_w  =(const float*)d_in[8];
  const float* sk_b  =(const float*)d_in[9];
  const float* sv_w  =(const float*)d_in[10];
  const float* sv_b  =(const float*)d_in[11];
  const float* an_g  =(const float*)d_in[12];
  const float* an_b  =(const float*)d_in[13];
  const float* wq    =(const float*)d_in[14];
  const float* wk    =(const float*)d_in[15];
  const float* wv    =(const float*)d_in[16];
  const float* wo    =(const float*)d_in[17];
  const float* wo_b  =(const float*)d_in[18];
  const float* fn_g  =(const float*)d_in[19];
  const float* fn_b  =(const float*)d_in[20];
  const float* w1    =(const float*)d_in[21];
  const float* b1    =(const float*)d_in[22];
  const float* w2    =(const float*)d_in[23];
  const float* b2    =(const float*)d_in[24];
  const float* fln_g =(const float*)d_in[25];
  const float* fln_b =(const float*)d_in[26];
  float* out = (float*)d_out;

  float* ws = (float*)d_ws;
  float* tokens  = ws;  ws += 4194304;  // 16 MB (start of actF 32MB span)
  ws += 4194304;                        // 16 MB actF second half
  float* Xc      = ws;  ws += 4194304;  // fp32 residual
  float* actAf   = ws;  ws += 2097152;  // bf16 16384x256
  float* wqTf    = ws;  ws += 524288;
  float* w1Tf    = ws;  ws += 1048576;
  float* w2Tf    = ws;  ws += 1048576;
  float* qkBf    = ws;  ws += 262144;   // bf16 [2][16][64][256]
  float* vwoTf   = ws;  ws += 262144;   // bf16 [2][16][256][64]
  float* kvk     = ws;  ws += 131072;
  float* kvv     = ws;  ws += 131072;
  float* kk2     = ws;  ws += 8192;
  float* kb      = ws;  ws += 32;
  float* vsc     = ws;  ws += 64;
  float* scores  = ws;  ws += 16384;
  long long* psumsI = (long long*)ws;  ws += 32;   // 16 x 8B
  int* rank      = (int*)ws;  ws += 16384;
  int* cidx      = (int*)ws;  ws += 16384;

  __hip_bfloat16* actA  = (__hip_bfloat16*)actAf;
  __hip_bfloat16* actF  = (__hip_bfloat16*)tokens;   // 16384x1024 bf16 span
  __hip_bfloat16* wqT   = (__hip_bfloat16*)wqTf;
  __hip_bfloat16* w1T   = (__hip_bfloat16*)w1Tf;
  __hip_bfloat16* w2T   = (__hip_bfloat16*)w2Tf;
  __hip_bfloat16* qkBuf = (__hip_bfloat16*)qkBf;
  __hip_bfloat16* vwoT  = (__hip_bfloat16*)vwoTf;

  scorer_kernel<<<32,256,0,stream>>>(m, sk_w, sk_b, sv_w, sv_b, sq_w, sq_b,
                                     kk2, kb, vsc);
  proj_prep_kernel<<<2560,256,0,stream>>>(
      x, proj_w, proj_b, lnp_g, lnp_b, kk2, kb, vsc,
      tokens, scores, rank, psumsI,
      m, an_g, an_b, wk, wv, kvk, kvv,
      wq, w1, w2, wqT, w1T, w2T);
  rank_qkvwo_kernel<<<1280,256,0,stream>>>(scores, rank, kvk, kvv, wqT, wo,
                                           qkBuf, vwoT);
  rank_finalize_kernel<<<64,256,0,stream>>>(rank, scores, cidx, psumsI);
  gather_ln_kernel<<<2048,256,0,stream>>>(tokens, cidx, Xc, actA, an_g, an_b);

  // layer 0
  fused_attn_kernel<<<dim3(32,16),256,0,stream>>>(
      actA, qkBuf, vwoT, wo_b, fn_g, fn_b, Xc, actA);
  ff1_gemm<<<dim3(8,16,16),256,0,stream>>>(
      actA, (long)SS*DD, w1T, (long)LL*FFD*DD,
      b1, LL*FFD, actF, FFD, (long)SS*FFD);
  ff2_fused_kernel<false><<<dim3(32,16),256,0,stream>>>(
      actF, w2T, b2, Xc, an_g + DD, an_b + DD, actA,
      nullptr, nullptr, nullptr);
  // layer 1
  fused_attn_kernel<<<dim3(32,16),256,0,stream>>>(
      actA, qkBuf + (long)16*64*256, vwoT + (long)16*256*64,
      wo_b + DD, fn_g + DD, fn_b + DD, Xc, actA);
  ff1_gemm<<<dim3(8,16,16),256,0,stream>>>(
      actA, (long)SS*DD, w1T + (long)FFD*DD, (long)LL*FFD*DD,
      b1 + FFD, LL*FFD, actF, FFD, (long)SS*FFD);
  ff2_fused_kernel<true><<<dim3(32,16),256,0,stream>>>(
      actF, w2T + (long)DD*FFD, b2 + DD, Xc, fln_g, fln_b, nullptr,
      cidx, psumsI, out);
}

// Round 34
// 216.038 us; speedup vs baseline: 1.0675x; 1.0031x over previous
//
#include <hip/hip_runtime.h>
#include <hip/hip_bf16.h>
#include <math.h>

// Problem constants
#define BB 4
#define CC 128
#define NN 4096      // H*W
#define DD 256
#define INNER 512
#define FFD 1024
#define PP 4
#define LL 2
#define NT 8
#define SS 1024      // NN/PP
#define SCALE 0.0625f // 1/sqrt(256)

typedef __attribute__((ext_vector_type(8))) short bf16x8;
typedef __attribute__((ext_vector_type(8))) short short8;
typedef __attribute__((ext_vector_type(4))) short short4v;
typedef __attribute__((ext_vector_type(4))) float f32x4;

#define GLD_LDS16(g, l) __builtin_amdgcn_global_load_lds( \
    (const __attribute__((address_space(1))) void*)(g), \
    (__attribute__((address_space(3))) void*)(l), 16, 0, 0)

template<int NW>
__device__ inline float block_sum(float v, float* sbuf){
  #pragma unroll
  for (int mk=32; mk; mk>>=1) v += __shfl_xor(v, mk);
  int w = threadIdx.x>>6;
  if ((threadIdx.x&63)==0) sbuf[w]=v;
  __syncthreads();
  float r = 0.f;
  #pragma unroll
  for (int k=0;k<NW;k++) r += sbuf[k];
  __syncthreads();
  return r;
}

__device__ inline unsigned short bf16bits(float v){
  __hip_bfloat16 t = __float2bfloat16(v);
  unsigned short u;
  __builtin_memcpy(&u, &t, 2);
  return u;
}
__device__ inline float bf2f(unsigned short u){
  unsigned int x = ((unsigned int)u)<<16;
  float f;
  __builtin_memcpy(&f, &x, 4);
  return f;
}

// fast GELU: erf via Abramowitz-Stegun 7.1.26 (|eps| <= 1.5e-7)
__device__ inline float gelu_f(float x){
  float z  = x * 0.70710678118654752440f;
  float az = fabsf(z);
  float t  = 1.0f / (1.0f + 0.3275911f*az);
  float y  = t*(0.254829592f + t*(-0.284496736f + t*(1.421413741f +
             t*(-1.453152027f + t*1.061405429f))));
  float erfv = 1.0f - y*__expf(-az*az);
  erfv = (z < 0.0f) ? -erfv : erfv;
  return 0.5f*x*(1.0f+erfv);
}

// shared wconv tile helper: convert+transpose one 64x64 tile
__device__ inline void wconv_tile(const float* __restrict__ src,
                                  __hip_bfloat16* __restrict__ dst,
                                  int pl, int K, int N, int k0, int n0,
                                  float (*t)[65], int tid)
{
  #pragma unroll
  for (int i=0;i<4;i++){
    int idx = i*256+tid;
    int kk = idx>>4, n4 = idx&15;
    float4 v = *(const float4*)&src[((long)pl*K + k0+kk)*N + n0 + n4*4];
    t[kk][n4*4+0]=v.x; t[kk][n4*4+1]=v.y; t[kk][n4*4+2]=v.z; t[kk][n4*4+3]=v.w;
  }
  __syncthreads();
  #pragma unroll
  for (int i=0;i<4;i++){
    int idx = i*256+tid;
    int nn = idx>>4, k4 = idx&15;
    short4v o;
    o[0] = (short)bf16bits(t[k4*4+0][nn]);
    o[1] = (short)bf16bits(t[k4*4+1][nn]);
    o[2] = (short)bf16bits(t[k4*4+2][nn]);
    o[3] = (short)bf16bits(t[k4*4+3][nn]);
    *(short4v*)&dst[((long)pl*N + n0+nn)*K + k0 + k4*4] = o;
  }
}

// K0: scorer (kk2/kb/vsc), 32 blocks
__global__ __launch_bounds__(256) void scorer_kernel(
    const float* __restrict__ m, const float* __restrict__ sk_w,
    const float* __restrict__ sk_b, const float* __restrict__ sv_w,
    const float* __restrict__ sv_b, const float* __restrict__ sq_w,
    const float* __restrict__ sq_b,
    float* __restrict__ kk2, float* __restrict__ kb, float* __restrict__ vsc)
{
  __shared__ float ms[256];
  __shared__ float ks[256];
  __shared__ float sbuf[4];
  int bj = blockIdx.x;
  int tid = threadIdx.x;
  ms[tid] = m[bj*DD + tid];
  __syncthreads();
  float acc=0.f;
  #pragma unroll 8
  for(int c=0;c<DD;c++) acc = fmaf(ms[c], sk_w[c*DD + tid], acc);
  ks[tid] = acc + sk_b[tid];
  float sv = block_sum<4>(ms[tid]*sv_w[tid], sbuf);
  if(tid==0) vsc[bj] = sv + sv_b[0];
  __syncthreads();
  const float* wr = sq_w + (long)tid*DD;
  float a2 = 0.f;
  #pragma unroll 4
  for (int c=0; c<DD; c+=4){
    float4 wvv = *(const float4*)(wr + c);
    a2 = fmaf(wvv.x, ks[c+0], fmaf(wvv.y, ks[c+1], fmaf(wvv.z, ks[c+2], fmaf(wvv.w, ks[c+3], a2))));
  }
  kk2[bj*DD + tid] = a2;
  float kbv = block_sum<4>(sq_b[tid]*ks[tid], sbuf);
  if (tid==0) kb[bj] = kbv;
}

// K1 MERGED, latency-bound work FIRST: [0,256) K/V; [256,1024) wconv l0
// (wq all + w1[l0] + w2[l0]); [1024,2048) proj+LN+scores.
__global__ __launch_bounds__(256) void proj_prep_kernel(
    const float* __restrict__ x, const float* __restrict__ proj_w,
    const float* __restrict__ proj_b, const float* __restrict__ lnp_g,
    const float* __restrict__ lnp_b, const float* __restrict__ kk2,
    const float* __restrict__ kb, const float* __restrict__ vsc,
    float* __restrict__ tokens, float* __restrict__ scores,
    int* __restrict__ rank, long long* __restrict__ psumsI,
    const float* __restrict__ m, const float* __restrict__ an_g,
    const float* __restrict__ an_b, const float* __restrict__ wk,
    const float* __restrict__ wv, float* __restrict__ kvk,
    float* __restrict__ kvv,
    const float* __restrict__ wq, const float* __restrict__ w1,
    const float* __restrict__ w2,
    __hip_bfloat16* __restrict__ wqT, __hip_bfloat16* __restrict__ w1T,
    __hip_bfloat16* __restrict__ w2T)
{
  __shared__ union {
    struct {
      float ys[16][260];
      float kj[8][260];
      float kbs[8], vs[8], mu_s[16], rs_s[16];
      float lg[16][8];
    } pr;
    struct { float t[64][65]; } wc;
    struct { float mn[256]; float sbuf[4]; } kv;
  } sm;
  int z = blockIdx.x;
  int tid = threadIdx.x;

  if (z < 256){
    // ---- K/V precompute (latency-bound, dispatch first) ----
    float* mn = sm.kv.mn;
    float* sbuf = sm.kv.sbuf;
    int idx = z;
    int j = idx & 7, b = (idx>>3)&3, pl = idx>>5;
    float v = m[(b*NT+j)*DD + tid];
    float s = block_sum<4>(v, sbuf);
    float mu = s*(1.0f/256.0f);
    float dv = v-mu;
    float q = block_sum<4>(dv*dv, sbuf);
    float rs = rsqrtf(q*(1.0f/256.0f)+1e-5f);
    mn[tid] = dv*rs*an_g[pl*DD+tid] + an_b[pl*DD+tid];
    __syncthreads();
    float ka0=0.f, va0=0.f, ka1=0.f, va1=0.f;
    const float* wkb = wk + (long)pl*DD*INNER;
    const float* wvb = wv + (long)pl*DD*INNER;
    #pragma unroll 8
    for (int c=0;c<DD;c++){
      float mc = mn[c];
      const float* wkr = wkb + (long)c*INNER;
      const float* wvr = wvb + (long)c*INNER;
      ka0 = fmaf(mc, wkr[tid], ka0);
      ka1 = fmaf(mc, wkr[tid+256], ka1);
      va0 = fmaf(mc, wvr[tid], va0);
      va1 = fmaf(mc, wvr[tid+256], va1);
    }
    long off = ((long)pl*BB + b)*(NT*INNER) + j*INNER;
    kvk[off+tid]=ka0; kvk[off+tid+256]=ka1;
    kvv[off+tid]=va0; kvv[off+tid+256]=va1;
  } else if (z < 1024){
    // ---- weight convert+transpose, layer-0 set: wq all + w1[l0] + w2[l0] ----
    int z2 = z - 256;
    if (z2 < 256){
      int pl = z2/32, r2 = z2%32;
      wconv_tile(wq, wqT, pl, DD, INNER, (r2/8)*64, (r2%8)*64, sm.wc.t, tid);
    } else if (z2 < 512){
      int rel = z2-256;
      int p = rel/64, r2 = rel%64;
      wconv_tile(w1, w1T, p*2, DD, FFD, (r2/16)*64, (r2%16)*64, sm.wc.t, tid);
    } else {
      int rel = z2-512;
      int p = rel/64, r2 = rel%64;
      wconv_tile(w2, w2T, p*2, FFD, DD, (r2/4)*64, (r2%4)*64, sm.wc.t, tid);
    }
  } else {
    // ---- proj + LN + scores (compute-bound, streams in behind prep) ----
    int zz = z - 1024;
    int b  = zz >> 8;
    int n0 = (zz & 255) * 16;
    if (tid < 16) rank[b*NN + n0 + tid] = 0;
    if (zz == 0 && tid < 16) psumsI[tid] = 0;
    float (*ys)[260] = sm.pr.ys;
    float (*kj)[260] = sm.pr.kj;
    float* kbs = sm.pr.kbs; float* vs = sm.pr.vs;
    float* mu_s = sm.pr.mu_s; float* rs_s = sm.pr.rs_s;
    float (*lg)[8] = sm.pr.lg;
    #pragma unroll
    for (int i=0;i<8;i++){
      int idx = i*256 + tid;
      int r = idx >> 8, c = idx & 255;
      kj[r][c] = kk2[(b*NT + r)*DD + c];
    }
    if (tid < 8){ kbs[tid] = kb[b*NT+tid]; vs[tid] = vsc[b*NT+tid]; }
    float acc[16];
    #pragma unroll
    for (int t=0;t<16;t++) acc[t]=0.f;
    const float* xb = x + (long)(b*CC)*NN + n0;
    for (int c0=0;c0<CC;c0+=4){
      float w0 = proj_w[(c0+0)*DD + tid];
      float w1_ = proj_w[(c0+1)*DD + tid];
      float w2_ = proj_w[(c0+2)*DD + tid];
      float w3_ = proj_w[(c0+3)*DD + tid];
      const float* x0 = xb + (long)(c0+0)*NN;
      const float* x1 = xb + (long)(c0+1)*NN;
      const float* x2 = xb + (long)(c0+2)*NN;
      const float* x3 = xb + (long)(c0+3)*NN;
      #pragma unroll
      for (int t=0;t<16;t++){
        acc[t] = fmaf(x0[t],w0,fmaf(x1[t],w1_,fmaf(x2[t],w2_,fmaf(x3[t],w3_,acc[t]))));
      }
    }
    float pb = proj_b[tid];
    #pragma unroll
    for (int t=0;t<16;t++) ys[t][tid] = acc[t] + pb;
    __syncthreads();
    int w = tid>>6, lane = tid&63;
    for (int k=0;k<4;k++){
      int t = w*4+k;
      float s = ys[t][lane] + ys[t][lane+64] + ys[t][lane+128] + ys[t][lane+192];
      #pragma unroll
      for (int mk=32; mk; mk>>=1) s += __shfl_xor(s, mk);
      float mu = s*(1.0f/256.0f);
      float d0=ys[t][lane]-mu, d1=ys[t][lane+64]-mu, d2=ys[t][lane+128]-mu, d3=ys[t][lane+192]-mu;
      float q = d0*d0+d1*d1+d2*d2+d3*d3;
      #pragma unroll
      for (int mk=32; mk; mk>>=1) q += __shfl_xor(q, mk);
      if (lane==0){ mu_s[t]=mu; rs_s[t]=rsqrtf(q*(1.0f/256.0f)+1e-5f); }
    }
    __syncthreads();
    float g = lnp_g[tid], be = lnp_b[tid];
    #pragma unroll
    for (int t=0;t<16;t++){
      float nv = (ys[t][tid]-mu_s[t])*rs_s[t]*g + be;
      tokens[((long)(b*NN + n0 + t))*DD + tid] = nv;
      ys[t][tid] = nv;
    }
    __syncthreads();
    if (tid < 128){
      int t = tid>>3, j = tid&7;
      float a2 = 0.f;
      for (int c0=0;c0<DD;c0+=4){
        float4 tv = *(const float4*)&ys[t][c0];
        float4 kv2 = *(const float4*)&kj[j][c0];
        a2 = fmaf(tv.x,kv2.x,fmaf(tv.y,kv2.y,fmaf(tv.z,kv2.z,fmaf(tv.w,kv2.w,a2))));
      }
      lg[t][j] = (a2 + kbs[j]) * SCALE;
    }
    __syncthreads();
    if (tid < 16){
      float mx=-1e30f;
      #pragma unroll
      for(int j=0;j<NT;j++) mx=fmaxf(mx,lg[tid][j]);
      float s=0.f, sc=0.f;
      #pragma unroll
      for(int j=0;j<NT;j++){ float e=__expf(lg[tid][j]-mx); s+=e; sc+=e*vs[j]; }
      scores[b*NN + n0 + tid] = sc/s;
    }
  }
}

// K2 MERGED: [0,512) wconv l1 (w1[l1]+w2[l1], needed 3 launches later);
// [512,768) qkvwo; [768,1792) partial ranks
__global__ __launch_bounds__(256) void rank_qkvwo_kernel(
    const float* __restrict__ scores, int* __restrict__ rank,
    const float* __restrict__ kvk, const float* __restrict__ kvv,
    const __hip_bfloat16* __restrict__ wqT, const float* __restrict__ wo,
    __hip_bfloat16* __restrict__ qkBuf, __hip_bfloat16* __restrict__ vwoT,
    const float* __restrict__ w1, const float* __restrict__ w2,
    __hip_bfloat16* __restrict__ w1T, __hip_bfloat16* __restrict__ w2T)
{
  __shared__ union {
    struct { float ss[256]; } rk;
    struct { float kL[8][64]; float vL[8][64]; } qv;
    struct { float t[64][65]; } wc;
  } sm;
  int z = blockIdx.x;
  if (z < 512){
    // ---- deferred layer-1 weight conversion ----
    if (z < 256){
      int p = z/64, r2 = z%64;
      wconv_tile(w1, w1T, p*2+1, DD, FFD, (r2/16)*64, (r2%16)*64, sm.wc.t, threadIdx.x);
    } else {
      int rel = z-256;
      int p = rel/64, r2 = rel%64;
      wconv_tile(w2, w2T, p*2+1, FFD, DD, (r2/4)*64, (r2%4)*64, sm.wc.t, threadIdx.x);
    }
  } else if (z < 768){
    int zz = z - 512;                // zz = z3*8 + h
    int z3 = zz>>3, h = zz&7;
    int l = z3>>4, g = z3&15;
    int b = g>>2, p = g&3;
    int pl = p*LL + l;
    int c = threadIdx.x;
    float (*kL)[64] = sm.qv.kL;
    float (*vL)[64] = sm.qv.vL;
    {
      int j0 = c>>6, d0 = c&63;
      long off = ((long)pl*BB + b)*(NT*INNER) + h*64 + d0;
      kL[j0][d0]   = kvk[off + j0*INNER];
      vL[j0][d0]   = kvv[off + j0*INNER];
      kL[j0+4][d0] = kvk[off + (j0+4)*INNER];
      vL[j0+4][d0] = kvv[off + (j0+4)*INNER];
    }
    __syncthreads();
    float qa[8] = {0,0,0,0,0,0,0,0};
    float va[8] = {0,0,0,0,0,0,0,0};
    const __hip_bfloat16* wqp = wqT + ((long)pl*INNER + h*64)*DD + c;
    const float* wop = wo + ((long)pl*INNER + h*64)*DD + c;
    #pragma unroll 4
    for (int d=0; d<64; d++){
      float wqv = bf2f(*(const unsigned short*)(wqp + (long)d*DD));
      float wov = wop[(long)d*DD];
      #pragma unroll
      for (int j=0;j<8;j++){
        qa[j] = fmaf(kL[j][d], wqv, qa[j]);
        va[j] = fmaf(vL[j][d], wov, va[j]);
      }
    }
    __hip_bfloat16* qkg = qkBuf + (long)z3*64*256;
    __hip_bfloat16* vwg = vwoT + (long)z3*256*64;
    #pragma unroll
    for (int j=0;j<8;j++)
      qkg[(h*8+j)*256 + c] = __float2bfloat16(qa[j]*SCALE);
    short8 o;
    #pragma unroll
    for (int j=0;j<8;j++) o[j] = (short)bf16bits(va[j]);
    *(short8*)(vwg + c*64 + h*8) = o;
  } else {
    int zz = z - 768;
    int b  = zz >> 8;
    int it = (zz >> 4) & 15;
    int jt = zz & 15;
    int i = it*256 + threadIdx.x;
    float si = scores[b*NN + i];
    sm.rk.ss[threadIdx.x] = scores[b*NN + jt*256 + threadIdx.x];
    __syncthreads();
    int jbase = jt*256;
    int cnt = 0;
    #pragma unroll 4
    for (int j=0;j<256;j++){
      float sj = sm.rk.ss[j];
      cnt += (sj > si) || (sj == si && (jbase+j) < i);
    }
    atomicAdd(&rank[b*NN+i], cnt);
  }
}

// K3b: cidx + fixed-point partition score sums (hierarchical, deterministic)
__global__ __launch_bounds__(256) void rank_finalize_kernel(
    const int* __restrict__ rank, const float* __restrict__ scores,
    int* __restrict__ cidx, long long* __restrict__ psumsI)
{
  __shared__ unsigned long long bins[PP];
  if (threadIdx.x < PP) bins[threadIdx.x] = 0ull;
  __syncthreads();
  int b = blockIdx.x >> 4;
  int i = (blockIdx.x & 15)*256 + threadIdx.x;
  int rk = rank[b*NN + i];
  int p = rk >> 10;
  cidx[(b*PP + p)*SS + (rk & (SS-1))] = i;
  long long iv = (long long)llrintf(scores[b*NN + i] * 268435456.0f); // 2^28
  atomicAdd(&bins[p], (unsigned long long)iv);
  __syncthreads();
  if (threadIdx.x < PP)
    atomicAdd((unsigned long long*)&psumsI[b*PP + threadIdx.x], bins[threadIdx.x]);
}

// K6: gather + LN(an[p,0]) fused
__global__ __launch_bounds__(256) void gather_ln_kernel(
    const float* __restrict__ tokens, const int* __restrict__ cidx,
    float* __restrict__ Xc, __hip_bfloat16* __restrict__ Y,
    const float* __restrict__ gamma, const float* __restrict__ beta)
{
  long slot = (long)blockIdx.x*8 + (threadIdx.x>>5);
  int l32 = threadIdx.x & 31;
  int b = (int)(slot >> 12);
  int p = (int)((slot>>10)&3);
  int i = cidx[slot];
  const float* src = tokens + ((long)b*NN + i)*DD + l32*8;
  float4 v0 = *(const float4*)src;
  float4 v1 = *(const float4*)(src+4);
  *(float4*)(Xc + slot*DD + l32*8) = v0;
  *(float4*)(Xc + slot*DD + l32*8 + 4) = v1;
  float s = v0.x+v0.y+v0.z+v0.w+v1.x+v1.y+v1.z+v1.w;
  #pragma unroll
  for (int mk=16; mk; mk>>=1) s += __shfl_xor(s, mk);
  float mu = s*(1.0f/256.0f);
  float vv[8] = {v0.x,v0.y,v0.z,v0.w,v1.x,v1.y,v1.z,v1.w};
  float q = 0.f;
  #pragma unroll
  for (int k=0;k<8;k++){ float d = vv[k]-mu; q += d*d; }
  #pragma unroll
  for (int mk=16; mk; mk>>=1) q += __shfl_xor(q, mk);
  float rs = rsqrtf(q*(1.0f/256.0f)+1e-5f);
  short8 o;
  #pragma unroll
  for (int k=0;k<8;k++){
    int d = l32*8+k;
    o[k] = (short)bf16bits((vv[k]-mu)*rs*gamma[p*(LL*DD)+d]+beta[p*(LL*DD)+d]);
  }
  *(short8*)(Y + slot*DD + l32*8) = o;
}

// K9: FF1 GEMM, 128x64 tile, K=256 (BK=64, dbuf). LDS 48KB -> 3 blocks/CU.
// Grid (8,16,16) = 2048 blocks. Same K accumulation order as before.
__global__ __launch_bounds__(256) void ff1_gemm(
    const __hip_bfloat16* __restrict__ A, long astride,
    const __hip_bfloat16* __restrict__ BT, long bpstride,
    const float* __restrict__ bias, int bias_pstride,
    __hip_bfloat16* __restrict__ C, int ldc, long cstride)
{
  int g = blockIdx.z;
  int p = g & 3;
  const __hip_bfloat16* Ag = A  + (long)g*astride + (long)blockIdx.x*128*DD;
  const __hip_bfloat16* Bg = BT + (long)p*bpstride + (long)blockIdx.y*64*DD;
  const float* biasg = bias + (long)p*bias_pstride;

  __shared__ __align__(16) __hip_bfloat16 Asm[2][128*64];
  __shared__ __align__(16) __hip_bfloat16 Bsm[2][64*64];

  int tid = threadIdx.x;
  int w = tid>>6, lane = tid&63;
  int lr = lane>>4, lc = lane&15;
  int ldsbase = tid & ~63;

  const __hip_bfloat16* aseg[4];
  const __hip_bfloat16* bseg[2];
  #pragma unroll
  for (int i=0;i<4;i++){
    int seg = i*256 + tid;
    int r = seg>>3, sl = seg&7;
    aseg[i] = Ag + (long)r*DD + (sl ^ (r&7))*8;
  }
  #pragma unroll
  for (int i=0;i<2;i++){
    int seg = i*256 + tid;
    int r = seg>>3, sl = seg&7;
    bseg[i] = Bg + (long)r*DD + (sl ^ (r&7))*8;
  }

  f32x4 acc[2][4] = {};

  #define STAGE1(buf) do { \
    _Pragma("unroll") \
    for (int i_=0;i_<4;i_++) \
      GLD_LDS16(aseg[i_], &Asm[buf][(i_*256 + ldsbase)*8]); \
    _Pragma("unroll") \
    for (int i_=0;i_<2;i_++) \
      GLD_LDS16(bseg[i_], &Bsm[buf][(i_*256 + ldsbase)*8]); \
    _Pragma("unroll") \
    for (int i_=0;i_<4;i_++) aseg[i_] += 64; \
    _Pragma("unroll") \
    for (int i_=0;i_<2;i_++) bseg[i_] += 64; \
  } while(0)

  STAGE1(0);
  asm volatile("s_waitcnt vmcnt(0)" ::: "memory");
  __syncthreads();

  for (int t=0; t<4; t++){
    int cur = t & 1;
    if (t+1 < 4) STAGE1(cur^1);
    #pragma unroll
    for (int kc=0;kc<2;kc++){
      bf16x8 af[2], bfr[4];
      #pragma unroll
      for (int mi=0;mi<2;mi++){
        int r = w*32 + mi*16 + lc;
        int s = kc*4 + lr;
        af[mi] = *(const bf16x8*)(&Asm[cur][r*64 + (s ^ (r&7))*8]);
      }
      #pragma unroll
      for (int ni=0;ni<4;ni++){
        int r = ni*16 + lc;
        int s = kc*4 + lr;
        bfr[ni] = *(const bf16x8*)(&Bsm[cur][r*64 + (s ^ (r&7))*8]);
      }
      #pragma unroll
      for (int mi=0;mi<2;mi++)
        #pragma unroll
        for (int ni=0;ni<4;ni++)
          acc[mi][ni] = __builtin_amdgcn_mfma_f32_16x16x32_bf16(af[mi], bfr[ni], acc[mi][ni], 0, 0, 0);
    }
    if (t+1 < 4) asm volatile("s_waitcnt vmcnt(0)" ::: "memory");
    __syncthreads();
  }
  #undef STAGE1

  __hip_bfloat16* Cg = C + (long)g*cstride;
  #pragma unroll
  for (int ni=0;ni<4;ni++){
    int col = blockIdx.y*64 + ni*16 + lc;
    float bv = biasg[col];
    #pragma unroll
    for (int mi=0;mi<2;mi++){
      int row = blockIdx.x*128 + w*32 + mi*16 + lr*4;
      #pragma unroll
      for (int j=0;j<4;j++){
        float v = acc[mi][ni][j] + bv;
        v = gelu_f(v);
        Cg[(long)(row+j)*ldc + col] = __float2bfloat16(v);
      }
    }
  }
}

// FF2 fused: 32x256 full-row tile, K=1024 (BK=64, dbuf). 512 blocks -> 2/CU.
template<bool LAST>
__global__ __launch_bounds__(256) void ff2_fused_kernel(
    const __hip_bfloat16* __restrict__ F,
    const __hip_bfloat16* __restrict__ w2l,
    const float* __restrict__ b2l,
    float* __restrict__ Xc,
    const float* __restrict__ g_ln,
    const float* __restrict__ b_ln,
    __hip_bfloat16* __restrict__ actOut,
    const int* __restrict__ cidx,
    const long long* __restrict__ psumsI,
    float* __restrict__ out)
{
  int rb = blockIdx.x;
  int g  = blockIdx.y;
  int p  = g & 3;
  const __hip_bfloat16* Ag = F + ((long)g*SS + rb*32)*FFD;
  const __hip_bfloat16* Bg = w2l + (long)p*((long)LL*DD*FFD);

  __shared__ __align__(16) __hip_bfloat16 As[2][32*64];
  __shared__ __align__(16) __hip_bfloat16 Bs[2][256*64];

  int tid = threadIdx.x;
  int w = tid>>6, lane = tid&63;
  int lr = lane>>4, lc = lane&15;
  int ldsbase = tid & ~63;

  const __hip_bfloat16* aseg;
  const __hip_bfloat16* bseg[8];
  {
    int seg = tid;
    int r = seg>>3, sl = seg&7;
    aseg = Ag + (long)r*FFD + (sl ^ (r&7))*8;
  }
  #pragma unroll
  for (int i=0;i<8;i++){
    int seg = i*256 + tid;
    int r = seg>>3, sl = seg&7;
    bseg[i] = Bg + (long)r*FFD + (sl ^ (r&7))*8;
  }

  f32x4 acc[2][4] = {};

  #define STAGE2(buf) do { \
    GLD_LDS16(aseg, &As[buf][ldsbase*8]); \
    _Pragma("unroll") \
    for (int i_=0;i_<8;i_++) \
      GLD_LDS16(bseg[i_], &Bs[buf][(i_*256 + ldsbase)*8]); \
    aseg += 64; \
    _Pragma("unroll") \
    for (int i_=0;i_<8;i_++) bseg[i_] += 64; \
  } while(0)

  STAGE2(0);
  asm volatile("s_waitcnt vmcnt(0)" ::: "memory");
  __syncthreads();

  for (int t=0; t<16; t++){
    int cur = t & 1;
    if (t+1 < 16) STAGE2(cur^1);
    #pragma unroll
    for (int kc=0;kc<2;kc++){
      bf16x8 af[2], bfr[4];
      #pragma unroll
      for (int mi=0;mi<2;mi++){
        int r = mi*16 + lc;
        int s = kc*4 + lr;
        af[mi] = *(const bf16x8*)(&As[cur][r*64 + (s ^ (r&7))*8]);
      }
      #pragma unroll
      for (int ni=0;ni<4;ni++){
        int c = w*64 + ni*16 + lc;
        int s = kc*4 + lr;
        bfr[ni] = *(const bf16x8*)(&Bs[cur][c*64 + (s ^ (c&7))*8]);
      }
      #pragma unroll
      for (int mi=0;mi<2;mi++)
        #pragma unroll
        for (int ni=0;ni<4;ni++)
          acc[mi][ni] = __builtin_amdgcn_mfma_f32_16x16x32_bf16(af[mi], bfr[ni], acc[mi][ni], 0, 0, 0);
    }
    if (t+1 < 16) asm volatile("s_waitcnt vmcnt(0)" ::: "memory");
    __syncthreads();
  }
  #undef STAGE2

  __syncthreads();
  float* pfl = (float*)&As[0][0];
  float* pfq = (float*)&As[0][0] + 128;
  float* Xg = Xc + (long)g*SS*DD + (long)rb*32*DD;

  float pwv = 1.0f;
  if (LAST){
    int b = g>>2;
    float ps[4];
    #pragma unroll
    for (int p2=0;p2<4;p2++)
      ps[p2] = (float)((double)psumsI[b*PP+p2] * (1.0/268435456.0/1024.0));
    float mxp = fmaxf(fmaxf(ps[0],ps[1]),fmaxf(ps[2],ps[3]));
    float e0=__expf(ps[0]-mxp), e1=__expf(ps[1]-mxp), e2=__expf(ps[2]-mxp), e3=__expf(ps[3]-mxp);
    float es = e0+e1+e2+e3;
    float ev = (p==0)?e0:(p==1)?e1:(p==2)?e2:e3;
    pwv = ev/es;
  }

  float srow[2][4], qrow[2][4];
  #pragma unroll
  for (int mi=0;mi<2;mi++)
    #pragma unroll
    for (int j=0;j<4;j++){ srow[mi][j]=0.f; qrow[mi][j]=0.f; }
  #pragma unroll
  for (int ni=0;ni<4;ni++){
    int col = w*64 + ni*16 + lc;
    float bv = b2l[p*(LL*DD) + col];
    #pragma unroll
    for (int mi=0;mi<2;mi++){
      int row = mi*16 + lr*4;
      #pragma unroll
      for (int j=0;j<4;j++){
        float v = Xg[(long)(row+j)*DD + col] + acc[mi][ni][j] + bv;
        if (!LAST) Xg[(long)(row+j)*DD + col] = v;
        if (LAST) v *= pwv;
        acc[mi][ni][j] = v;
        srow[mi][j] += v;
        qrow[mi][j] += v*v;
      }
    }
  }
  #pragma unroll
  for (int mi=0;mi<2;mi++)
    #pragma unroll
    for (int j=0;j<4;j++){
      float s2=srow[mi][j], q2=qrow[mi][j];
      s2 += __shfl_xor(s2,1); q2 += __shfl_xor(q2,1);
      s2 += __shfl_xor(s2,2); q2 += __shfl_xor(q2,2);
      s2 += __shfl_xor(s2,4); q2 += __shfl_xor(q2,4);
      s2 += __shfl_xor(s2,8); q2 += __shfl_xor(q2,8);
      srow[mi][j]=s2; qrow[mi][j]=q2;
    }
  if (lc==0){
    #pragma unroll
    for (int mi=0;mi<2;mi++)
      #pragma unroll
      for (int j=0;j<4;j++){
        int row = mi*16 + lr*4 + j;
        pfl[w*32+row] = srow[mi][j];
        pfq[w*32+row] = qrow[mi][j];
      }
  }
  __syncthreads();

  if (!LAST){
    __hip_bfloat16* Ya = actOut + ((long)g*SS + rb*32)*DD;
    const float* fg = g_ln + p*(LL*DD);
    const float* fb = b_ln + p*(LL*DD);
    #pragma unroll
    for (int mi=0;mi<2;mi++){
      #pragma unroll
      for (int j=0;j<4;j++){
        int row = mi*16 + lr*4 + j;
        float S = pfl[row] + pfl[32+row] + pfl[64+row] + pfl[96+row];
        float Q = pfq[row] + pfq[32+row] + pfq[64+row] + pfq[96+row];
        float mu = S*(1.0f/256.0f);
        float var = Q*(1.0f/256.0f) - mu*mu;
        float rs2 = rsqrtf(var + 1e-5f);
        #pragma unroll
        for (int ni=0;ni<4;ni++){
          int col = w*64 + ni*16 + lc;
          Ya[(long)row*DD + col] =
              __float2bfloat16((acc[mi][ni][j]-mu)*rs2*fg[col]+fb[col]);
        }
      }
    }
  } else {
    int b = g>>2;
    #pragma unroll
    for (int mi=0;mi<2;mi++){
      #pragma unroll
      for (int j=0;j<4;j++){
        int row = mi*16 + lr*4 + j;
        long slot = (long)g*SS + rb*32 + row;
        int i = cidx[slot];
        float S = pfl[row] + pfl[32+row] + pfl[64+row] + pfl[96+row];
        float Q = pfq[row] + pfq[32+row] + pfq[64+row] + pfq[96+row];
        float mu = S*(1.0f/256.0f);
        float var = Q*(1.0f/256.0f) - mu*mu;
        float rs2 = rsqrtf(var + 1e-5f);
        float* op = out + ((long)b*NN + i)*DD;
        #pragma unroll
        for (int ni=0;ni<4;ni++){
          int col = w*64 + ni*16 + lc;
          op[col] = (acc[mi][ni][j]-mu)*rs2*g_ln[col]+b_ln[col];
        }
      }
    }
  }
}

// K10: FUSED attention + fn-LayerNorm, 32-row tiles (grid (32,16) -> 2 blocks/CU)
__global__ __launch_bounds__(256) void fused_attn_kernel(
    const __hip_bfloat16* __restrict__ actA,
    const __hip_bfloat16* __restrict__ qk,
    const __hip_bfloat16* __restrict__ vwo,
    const float* __restrict__ wo_bl,
    const float* __restrict__ fn_gl,
    const float* __restrict__ fn_bl,
    float* __restrict__ Xc,
    __hip_bfloat16* __restrict__ actOut)
{
  int rb = blockIdx.x;
  int g  = blockIdx.y;
  int p  = g & 3;
  const __hip_bfloat16* Ag = actA + ((long)g*SS + rb*32)*DD;
  const __hip_bfloat16* Qg = qk  + (long)g*64*256;
  const __hip_bfloat16* Vg = vwo + (long)g*256*64;

  __shared__ __align__(16) __hip_bfloat16 sm[24576];
  int tid = threadIdx.x;
  int w = tid>>6, lane = tid&63;
  int lr = lane>>4, lc = lane&15;
  int ldsbase = tid & ~63;

  // Q: 64x256 at elem offset 8192 (32KB)
  #pragma unroll
  for (int i=0;i<8;i++){
    int seg = i*256 + tid;
    int r = seg>>5, sl = seg&31;
    int sg = sl ^ (r&7);
    GLD_LDS16(Qg + (long)r*256 + sg*8, &sm[8192 + (i*256 + ldsbase)*8]);
  }
  // A tile 0: 32x64 at elem offset 0 (4KB), dbuf at 2048
  {
    int r = tid>>3, sl = tid&7;
    int sg = sl ^ (r&7);
    GLD_LDS16(Ag + (long)r*DD + sg*8, &sm[0 + ldsbase*8]);
  }
  asm volatile("s_waitcnt vmcnt(0)" ::: "memory");
  __syncthreads();

  // QK^T: S = 32x64. Wave w: rows (w&1)*16, cols (w>>1)*32.
  f32x4 acc1[2] = {};
  for (int t=0; t<4; t++){
    int cur = t&1;
    if (t+1 < 4){
      int r = tid>>3, sl = tid&7;
      int sg = sl ^ (r&7);
      GLD_LDS16(Ag + (long)r*DD + (t+1)*64 + sg*8,
                &sm[(cur^1)*2048 + ldsbase*8]);
    }
    #pragma unroll
    for (int kc=0;kc<2;kc++){
      int r = (w&1)*16 + lc;
      int s = kc*4 + lr;
      bf16x8 af = *(const bf16x8*)(&sm[cur*2048 + r*64 + (s ^ (r&7))*8]);
      #pragma unroll
      for (int ni=0;ni<2;ni++){
        int rb_ = (w>>1)*32 + ni*16 + lc;
        int sb = t*8 + kc*4 + lr;
        bf16x8 bfr = *(const bf16x8*)(&sm[8192 + rb_*256 + (sb ^ (rb_&7))*8]);
        acc1[ni] = __builtin_amdgcn_mfma_f32_16x16x32_bf16(af, bfr, acc1[ni], 0, 0, 0);
      }
    }
    if (t+1 < 4) asm volatile("s_waitcnt vmcnt(0)" ::: "memory");
    __syncthreads();
  }

  // V: 256x64 at elem offset 8192 (32KB), overwrites Q
  #pragma unroll
  for (int i=0;i<8;i++){
    int seg = i*256 + tid;
    int r = seg>>3, sl = seg&7;
    int sg = sl ^ (r&7);
    GLD_LDS16(Vg + (long)r*64 + sg*8, &sm[8192 + (i*256 + ldsbase)*8]);
  }

  // softmax over each head's 8 kv (lanes differing in lc&7)
  float pv[2][4];
  #pragma unroll
  for (int ni=0;ni<2;ni++){
    #pragma unroll
    for (int j=0;j<4;j++){
      float v = acc1[ni][j];
      float mx = v;
      mx = fmaxf(mx, __shfl_xor(mx,1));
      mx = fmaxf(mx, __shfl_xor(mx,2));
      mx = fmaxf(mx, __shfl_xor(mx,4));
      float e = __expf(v - mx);
      float ssum = e;
      ssum += __shfl_xor(ssum,1);
      ssum += __shfl_xor(ssum,2);
      ssum += __shfl_xor(ssum,4);
      pv[ni][j] = e / ssum;
    }
  }
  // store P (32x64 bf16) at elem offset 0
  #pragma unroll
  for (int ni=0;ni<2;ni++){
    #pragma unroll
    for (int j=0;j<4;j++){
      int row = (w&1)*16 + lr*4 + j;
      int col = (w>>1)*32 + ni*16 + lc;
      int s = col>>3, e = col&7;
      sm[row*64 + ((s ^ (row&7))<<3) + e] = __float2bfloat16(pv[ni][j]);
    }
  }
  asm volatile("s_waitcnt vmcnt(0)" ::: "memory");
  __syncthreads();

  // PV: O = P(32x64) x V^T -> 32x256, waves split output cols (w*64)
  f32x4 acc2[2][4] = {};
  #pragma unroll
  for (int kc=0;kc<2;kc++){
    bf16x8 af[2], bfr[4];
    #pragma unroll
    for (int mi=0;mi<2;mi++){
      int r = mi*16 + lc;
      int s = kc*4 + lr;
      af[mi] = *(const bf16x8*)(&sm[r*64 + (s ^ (r&7))*8]);
    }
    #pragma unroll
    for (int ni=0;ni<4;ni++){
      int rb_ = w*64 + ni*16 + lc;
      int s = kc*4 + lr;
      bfr[ni] = *(const bf16x8*)(&sm[8192 + rb_*64 + (s ^ (rb_&7))*8]);
    }
    #pragma unroll
    for (int mi=0;mi<2;mi++)
      #pragma unroll
      for (int ni=0;ni<4;ni++)
        acc2[mi][ni] = __builtin_amdgcn_mfma_f32_16x16x32_bf16(af[mi], bfr[ni], acc2[mi][ni], 0, 0, 0);
  }

  __syncthreads();
  float* pfl = (float*)sm;
  float* pfq = (float*)sm + 128;
  float* Xg = Xc + (long)g*SS*DD + (long)rb*32*DD;
  float srow[2][4], qrow[2][4];
  #pragma unroll
  for (int mi=0;mi<2;mi++)
    #pragma unroll
    for (int j=0;j<4;j++){ srow[mi][j]=0.f; qrow[mi][j]=0.f; }
  #pragma unroll
  for (int ni=0;ni<4;ni++){
    int col = w*64 + ni*16 + lc;
    float bv = wo_bl[p*(LL*DD) + col];
    #pragma unroll
    for (int mi=0;mi<2;mi++){
      int row = mi*16 + lr*4;
      #pragma unroll
      for (int j=0;j<4;j++){
        float v = Xg[(long)(row+j)*DD + col] + acc2[mi][ni][j] + bv;
        Xg[(long)(row+j)*DD + col] = v;
        acc2[mi][ni][j] = v;
        srow[mi][j] += v;
        qrow[mi][j] += v*v;
      }
    }
  }
  #pragma unroll
  for (int mi=0;mi<2;mi++)
    #pragma unroll
    for (int j=0;j<4;j++){
      float s2=srow[mi][j], q2=qrow[mi][j];
      s2 += __shfl_xor(s2,1); q2 += __shfl_xor(q2,1);
      s2 += __shfl_xor(s2,2); q2 += __shfl_xor(q2,2);
      s2 += __shfl_xor(s2,4); q2 += __shfl_xor(q2,4);
      s2 += __shfl_xor(s2,8); q2 += __shfl_xor(q2,8);
      srow[mi][j]=s2; qrow[mi][j]=q2;
    }
  if (lc==0){
    #pragma unroll
    for (int mi=0;mi<2;mi++)
      #pragma unroll
      for (int j=0;j<4;j++){
        int row = mi*16 + lr*4 + j;
        pfl[w*32+row] = srow[mi][j];
        pfq[w*32+row] = qrow[mi][j];
      }
  }
  __syncthreads();
  __hip_bfloat16* Ya = actOut + ((long)g*SS + rb*32)*DD;
  const float* fg = fn_gl + p*(LL*DD);
  const float* fb = fn_bl + p*(LL*DD);
  #pragma unroll
  for (int mi=0;mi<2;mi++){
    #pragma unroll
    for (int j=0;j<4;j++){
      int row = mi*16 + lr*4 + j;
      float S = pfl[row] + pfl[32+row] + pfl[64+row] + pfl[96+row];
      float Q = pfq[row] + pfq[32+row] + pfq[64+row] + pfq[96+row];
      float mu = S*(1.0f/256.0f);
      float var = Q*(1.0f/256.0f) - mu*mu;
      float rs2 = rsqrtf(var + 1e-5f);
      #pragma unroll
      for (int ni=0;ni<4;ni++){
        int col = w*64 + ni*16 + lc;
        Ya[(long)row*DD + col] =
            __float2bfloat16((acc2[mi][ni][j]-mu)*rs2*fg[col]+fb[col]);
      }
    }
  }
}

extern "C" void kernel_launch(void* const* d_in, const int* in_sizes, int n_in,
                              void* d_out, int out_size, void* d_ws, size_t ws_size,
                              hipStream_t stream)
{
  (void)in_sizes; (void)n_in; (void)out_size; (void)ws_size;
  const float* x     =(const float*)d_in[0];
  const float* m     =(const float*)d_in[1];
  const float* proj_w=(const float*)d_in[2];
  const float* proj_b=(const float*)d_in[3];
  const float* lnp_g =(const float*)d_in[4];
  const float* lnp_b =(const float*)d_in[5];
  const float* sq_w  =(const float*)d_in[6];
  const float* sq_b  =(const float*)d_in[7];
  const float* sk_w  =(const float*)d_in[8];
  const float* sk_b  =(const float*)d_in[9];
  const float* sv_w  =(const float*)d_in[10];
  const float* sv_b  =(const float*)d_in[11];
  const float* an_g  =(const float*)d_in[12];
  const float* an_b  =(const float*)d_in[13];
  const float* wq    =(const float*)d_in[14];
  const float* wk    =(const float*)d_in[15];
  const float* wv    =(const float*)d_in[16];
  const float* wo    =(const float*)d_in[17];
  const float* wo_b  =(const float*)d_in[18];
  const float* fn_g  =(const float*)d_in[19];
  const float* fn_b  =(const float*)d_in[20];
  const float* w1    =(const float*)d_in[21];
  const float* b1    =(const float*)d_in[22];
  const float* w2    =(const float*)d_in[23];
  const float* b2    =(const float*)d_in[24];
  const float* fln_g =(const float*)d_in[25];
  const float* fln_b =(const float*)d_in[26];
  float* out = (float*)d_out;

  float* ws = (float*)d_ws;
  float* tokens  = ws;  ws += 4194304;  // 16 MB (start of actF 32MB span)
  ws += 4194304;                        // 16 MB actF second half
  float* Xc      = ws;  ws += 4194304;  // fp32 residual
  float* actAf   = ws;  ws += 2097152;  // bf16 16384x256
  float* wqTf    = ws;  ws += 524288;
  float* w1Tf    = ws;  ws += 1048576;
  float* w2Tf    = ws;  ws += 1048576;
  float* qkBf    = ws;  ws += 262144;   // bf16 [2][16][64][256]
  float* vwoTf   = ws;  ws += 262144;   // bf16 [2][16][256][64]
  float* kvk     = ws;  ws += 131072;
  float* kvv     = ws;  ws += 131072;
  float* kk2     = ws;  ws += 8192;
  float* kb      = ws;  ws += 32;
  float* vsc     = ws;  ws += 64;
  float* scores  = ws;  ws += 16384;
  long long* psumsI = (long long*)ws;  ws += 32;   // 16 x 8B
  int* rank      = (int*)ws;  ws += 16384;
  int* cidx      = (int*)ws;  ws += 16384;

  __hip_bfloat16* actA  = (__hip_bfloat16*)actAf;
  __hip_bfloat16* actF  = (__hip_bfloat16*)tokens;   // 16384x1024 bf16 span
  __hip_bfloat16* wqT   = (__hip_bfloat16*)wqTf;
  __hip_bfloat16* w1T   = (__hip_bfloat16*)w1Tf;
  __hip_bfloat16* w2T   = (__hip_bfloat16*)w2Tf;
  __hip_bfloat16* qkBuf = (__hip_bfloat16*)qkBf;
  __hip_bfloat16* vwoT  = (__hip_bfloat16*)vwoTf;

  scorer_kernel<<<32,256,0,stream>>>(m, sk_w, sk_b, sv_w, sv_b, sq_w, sq_b,
                                     kk2, kb, vsc);
  proj_prep_kernel<<<2048,256,0,stream>>>(
      x, proj_w, proj_b, lnp_g, lnp_b, kk2, kb, vsc,
      tokens, scores, rank, psumsI,
      m, an_g, an_b, wk, wv, kvk, kvv,
      wq, w1, w2, wqT, w1T, w2T);
  rank_qkvwo_kernel<<<1792,256,0,stream>>>(scores, rank, kvk, kvv, wqT, wo,
                                           qkBuf, vwoT, w1, w2, w1T, w2T);
  rank_finalize_kernel<<<64,256,0,stream>>>(rank, scores, cidx, psumsI);
  gather_ln_kernel<<<2048,256,0,stream>>>(tokens, cidx, Xc, actA, an_g, an_b);

  // layer 0
  fused_attn_kernel<<<dim3(32,16),256,0,stream>>>(
      actA, qkBuf, vwoT, wo_b, fn_g, fn_b, Xc, actA);
  ff1_gemm<<<dim3(8,16,16),256,0,stream>>>(
      actA, (long)SS*DD, w1T, (long)LL*FFD*DD,
      b1, LL*FFD, actF, FFD, (long)SS*FFD);
  ff2_fused_kernel<false><<<dim3(32,16),256,0,stream>>>(
      actF, w2T, b2, Xc, an_g + DD, an_b + DD, actA,
      nullptr, nullptr, nullptr);
  // layer 1
  fused_attn_kernel<<<dim3(32,16),256,0,stream>>>(
      actA, qkBuf + (long)16*64*256, vwoT + (long)16*256*64,
      wo_b + DD, fn_g + DD, fn_b + DD, Xc, actA);
  ff1_gemm<<<dim3(8,16,16),256,0,stream>>>(
      actA, (long)SS*DD, w1T + (long)FFD*DD, (long)LL*FFD*DD,
      b1 + FFD, LL*FFD, actF, FFD, (long)SS*FFD);
  ff2_fused_kernel<true><<<dim3(32,16),256,0,stream>>>(
      actF, w2T + (long)DD*FFD, b2 + DD, Xc, fln_g, fln_b, nullptr,
      cidx, psumsI, out);
}